// Round 12
// baseline (468.535 us; speedup 1.0000x reference)
//
#include <hip/hip_runtime.h>
#include <cmath>

// Match XLA/numpy non-fused mul+add rounding everywhere (IoU / decode bit-faithfulness).
#pragma clang fp contract(off)

namespace {
constexpr int NIMG = 8;
constexpr int NLVL = 5;
constexpr int LH[5]   = {208,104,52,26,13};
constexpr int LW[5]   = {336,168,84,42,21};
constexpr int LSTR[5] = {4,8,16,32,64};
constexpr int HWA[5]  = {209664,52416,13104,3276,819};
constexpr int KSEL[5] = {2000,2000,2000,2000,819};
constexpr int SOFF[5] = {0,2000,4000,6000,8000};
constexpr int MTOT    = 8819;
constexpr int CAP     = 6144;          // per-(img,lvl) candidate cap (expect <= ~2600)
constexpr int NPAIR   = NIMG*NLVL;     // 40
constexpr int CCUM[5] = {52,65,69,70,71};  // cumulative ceil(HWA/4096) per level
constexpr int BLK_PER_IMG = 71;
constexpr int MASK_W  = 32;            // u64 words per NMS mask row (covers 2048 cols)
constexpr int OUTK    = 1000;

// workspace byte offsets (all 16B-aligned where needed)
constexpr size_t OFF_HIST   = 0;              // 40*4096*4      = 655360
constexpr size_t OFF_PKC    = 0;              // 40*2048*4 = 327680, aliases hist (dead after k_scan)
constexpr size_t OFF_CNT    = 655360;         // 40*4           = 160
constexpr size_t OFF_THR    = 655520;         // 40*4           = 160
constexpr size_t ZERO_BYTES = 655680;         // memset range (hist+cnt+thr)
constexpr size_t OFF_CAND   = 655872;         // 40*6144*4      = 983040  -> 1638912
constexpr size_t OFF_SELIDX = 1638912;        // 8*8819*4       = 282208  -> 1921120
constexpr size_t OFF_SELKEY = 1921120;        // 8*8819*8       = 564416  -> 2485536
constexpr size_t OFF_SELSC  = 2485536;        // 8*8819*4       = 282208  -> 2767744
constexpr size_t OFF_SELBOX = 2767744;        // 8*8819*16      = 1128832 -> 3896576
constexpr size_t OFF_MASK   = 3896576;        // 40*2000*32*8   = 20480000-> 24376576
constexpr size_t OFF_CKEY   = OFF_MASK;       // 40*6144*8 = 1.97MB aliases maskbuf (dead by k_masks)
constexpr size_t OFF_KEEP   = 24376576;       // 40*32*8        = 10240   -> 24386816
}

struct Ins {
  const float* cls[5];
  const float* reg[5];
  const int* ih;
  const int* iw;
};

__device__ __forceinline__ void decode_block(int b, int& img, int& lvl, int& chunk) {
  img = b / BLK_PER_IMG;
  int rb = b - img*BLK_PER_IMG;
  if      (rb < CCUM[0]) { lvl=0; chunk=rb; }
  else if (rb < CCUM[1]) { lvl=1; chunk=rb-CCUM[0]; }
  else if (rb < CCUM[2]) { lvl=2; chunk=rb-CCUM[1]; }
  else if (rb < CCUM[3]) { lvl=3; chunk=rb-CCUM[2]; }
  else                   { lvl=4; chunk=0; }
}

// order-preserving float->u32 map (total order over floats)
__device__ __forceinline__ unsigned mapbits(float x) {
  unsigned u = __float_as_uint(x);
  return u ^ (unsigned)(((int)u >> 31) | (int)0x80000000);
}

// fp32 sigmoid with correctly-rounded exp step: matches 1/(1+exp_f32(-x)) pipeline
__device__ __forceinline__ float sigmoid_ref(float x) {
  float e = (float)exp(-(double)x);   // correctly-rounded f32 exp(-x)
  return 1.0f / (1.0f + e);           // exact-IEEE add + div
}

__device__ __forceinline__ unsigned long long readlane_u64(unsigned long long v, int lane) {
  unsigned lo = (unsigned)__builtin_amdgcn_readlane((int)(unsigned)v, lane);
  unsigned hi = (unsigned)__builtin_amdgcn_readlane((int)(unsigned)(v >> 32), lane);
  return ((unsigned long long)hi << 32) | (unsigned long long)lo;
}

// ---- K1: per-(img,lvl) 12-bit histogram of mapped logit bits ----
__global__ void k_hist(Ins in, unsigned* __restrict__ hist) {
  int img, lvl, chunk; decode_block(blockIdx.x, img, lvl, chunk);
  __shared__ unsigned lh[4096];
  for (int i = threadIdx.x; i < 4096; i += 256) lh[i] = 0;
  __syncthreads();
  const float* src = in.cls[lvl] + (size_t)img * HWA[lvl];
  int base = chunk * 4096;
  #pragma unroll
  for (int j = 0; j < 16; j++) {
    int e = base + j*256 + threadIdx.x;
    if (e < HWA[lvl]) {
      unsigned m = mapbits(src[e]);
      atomicAdd(&lh[m >> 20], 1u);
    }
  }
  __syncthreads();
  unsigned* gh = hist + (img*NLVL + lvl) * 4096;
  for (int i = threadIdx.x; i < 4096; i += 256)
    if (lh[i]) atomicAdd(&gh[i], lh[i]);
}

// ---- K2: find highest bin-edge with suffix count >= k ----
__global__ void k_scan(const unsigned* __restrict__ hist, unsigned* __restrict__ thr) {
  int pair = blockIdx.x; int lvl = pair % NLVL;
  const unsigned* h = hist + (size_t)pair * 4096;
  __shared__ unsigned part[256];
  unsigned s = 0;
  #pragma unroll
  for (int i = 0; i < 16; i++) s += h[threadIdx.x*16 + i];
  part[threadIdx.x] = s;
  __syncthreads();
  if (threadIdx.x == 0) {
    unsigned k = (unsigned)KSEL[lvl];
    unsigned cum = 0;
    unsigned edge = 0;
    for (int t = 255; t >= 0; t--) {
      if (cum + part[t] >= k) {
        for (int b = t*16 + 15; b >= t*16; b--) {
          cum += h[b];
          if (cum >= k) { edge = (unsigned)b; break; }
        }
        thr[pair] = edge << 20;
        return;
      }
      cum += part[t];
    }
    thr[pair] = 0u;
  }
}

// ---- K3: compact candidates; LDS block aggregation -> ONE global atomic/block ----
__global__ void __launch_bounds__(256) k_compact(Ins in, const unsigned* __restrict__ thr,
                          unsigned* __restrict__ cnt, unsigned* __restrict__ cand) {
  int img, lvl, chunk; decode_block(blockIdx.x, img, lvl, chunk);
  int pair = img*NLVL + lvl;
  unsigned T = thr[pair];
  const float* src = in.cls[lvl] + (size_t)img * HWA[lvl];
  int hw = LH[lvl] * LW[lvl];
  int base = chunk * 4096;
  int lid = threadIdx.x & 63;
  __shared__ unsigned lbuf[4096];      // block covers <=4096 elements: p always fits
  __shared__ unsigned lc, gbase;
  if (threadIdx.x == 0) lc = 0;
  __syncthreads();
  #pragma unroll
  for (int j = 0; j < 16; j++) {
    int e = base + j*256 + threadIdx.x;
    bool sel = (e < HWA[lvl]) && (mapbits(src[e]) >= T);
    unsigned long long mask = __ballot(sel);
    if (mask != 0ull) {
      int leader = __ffsll((long long)mask) - 1;
      unsigned wb = 0;
      if (lid == leader) wb = atomicAdd(&lc, (unsigned)__popcll(mask));  // LDS atomic
      wb = (unsigned)__shfl((int)wb, leader, 64);
      if (sel) {
        unsigned p = wb + (unsigned)__popcll(mask & ((1ull << lid) - 1ull));
        int a = e / hw;            // NCHW: e = a*hw + r
        int r = e - a*hw;
        lbuf[p] = (unsigned)(r*3 + a);  // score-space idx
      }
    }
  }
  __syncthreads();
  if (threadIdx.x == 0) gbase = atomicAdd(&cnt[pair], lc);  // one global atomic/block
  __syncthreads();
  unsigned nsel = lc, gb = gbase;
  for (unsigned t = threadIdx.x; t < nsel; t += 256) {
    unsigned p = gb + t;
    if (p < CAP) cand[(size_t)pair*CAP + p] = lbuf[t];      // coalesced
  }
}

// ---- K3b: compute sort keys ONCE per candidate (hoists dp-exp out of k_rank tiles) ----
__global__ void k_keys(Ins in, const unsigned* __restrict__ cntA,
                       const unsigned* __restrict__ cand,
                       unsigned long long* __restrict__ ckey) {
  int pair = blockIdx.y;
  int img = pair / NLVL, lvl = pair % NLVL;
  int c = min((int)cntA[pair], CAP);
  int j = blockIdx.x*256 + threadIdx.x;
  if (j >= c) return;
  unsigned idx = cand[(size_t)pair*CAP + j];
  int a = (int)(idx % 3u), r = (int)(idx / 3u);
  int hw = LH[lvl]*LW[lvl];
  float s = sigmoid_ref(in.cls[lvl][(size_t)img*HWA[lvl] + a*hw + r]);
  unsigned pack = ((unsigned)lvl << 18) | idx;   // < 2^21
  ckey[(size_t)pair*CAP + j] = ((unsigned long long)__float_as_uint(s) << 21)
                             | (unsigned long long)(0x1FFFFFu - pack);  // desc score, asc (lvl,idx)
}

// ---- K4: per-level exact rank (score desc, idx asc); scatter top-k into slots ----
__global__ void __launch_bounds__(256) k_rank(const unsigned* __restrict__ cntA,
                       const unsigned* __restrict__ cand,
                       const unsigned long long* __restrict__ ckey,
                       unsigned* __restrict__ sel_idx,
                       unsigned long long* __restrict__ sel_key,
                       float* __restrict__ sel_sc) {
  int pair = blockIdx.y; int tile = blockIdx.x;
  int img = pair / NLVL, lvl = pair % NLVL;
  int c = min((int)cntA[pair], CAP);
  if (tile*256 >= c) return;
  __shared__ unsigned long long keys[CAP];
  const unsigned long long* kp = ckey + (size_t)pair*CAP;
  for (int j = threadIdx.x; j < c; j += 256) keys[j] = kp[j];
  __syncthreads();
  int jj = tile*256 + threadIdx.x;
  if (jj >= c) return;
  unsigned long long mykey = keys[jj];
  int rk = 0;
  for (int j = 0; j < c; j++) rk += (keys[j] > mykey) ? 1 : 0;  // LDS broadcast
  if (rk < KSEL[lvl]) {
    int slot = img*MTOT + SOFF[lvl] + rk;
    sel_idx[slot] = cand[(size_t)pair*CAP + jj];
    sel_key[slot] = mykey;
    sel_sc[slot]  = __uint_as_float((unsigned)(mykey >> 21));
  }
}

// ---- K5: decode boxes (exact mmdet DeltaXYWH replication, clipped) ----
__global__ void k_decode(Ins in, const unsigned* __restrict__ sel_idx,
                         float* __restrict__ sel_box) {
  int t = blockIdx.x*256 + threadIdx.x;
  if (t >= NIMG*MTOT) return;
  int img = t / MTOT, pos = t - img*MTOT;
  int lvl = pos<2000?0 : pos<4000?1 : pos<6000?2 : pos<8000?3 : 4;
  unsigned idx = sel_idx[img*MTOT + pos];
  int a = (int)(idx % 3u);
  int r = (int)(idx / 3u);
  int Wl = LW[lvl]; int hw = LH[lvl]*Wl;
  int x = r % Wl, y = r / Wl;
  const float* rg = in.reg[lvl] + (size_t)img * 4 * HWA[lvl];  // 12*H*W
  float dx = rg[(a*4+0)*hw + r];
  float dy = rg[(a*4+1)*hw + r];
  float dw = rg[(a*4+2)*hw + r];
  float dh = rg[(a*4+3)*hw + r];
  float ratio = (a==0) ? 0.5f : (a==1) ? 1.0f : 2.0f;
  float hr = sqrtf(ratio);
  float wr = 1.0f / hr;
  float st = (float)LSTR[lvl];
  float wsz = st * wr * 8.0f;
  float hsz = st * hr * 8.0f;
  float xs = (float)x * st, ys = (float)y * st;
  float x1 = xs - wsz*0.5f, x2 = xs + wsz*0.5f;
  float y1 = ys - hsz*0.5f, y2 = ys + hsz*0.5f;
  float px = (x1 + x2) * 0.5f, py = (y1 + y2) * 0.5f;
  float pw = x2 - x1,          ph = y2 - y1;
  const float MR = 4.135166556742356f;
  dw = fminf(fmaxf(dw, -MR), MR);
  dh = fminf(fmaxf(dh, -MR), MR);
  float gx = px + pw*dx, gy = py + ph*dy;
  float gw = pw * (float)exp((double)dw);   // correctly-rounded f32 exp
  float gh = ph * (float)exp((double)dh);
  float Wi = (float)(*in.iw), Hi = (float)(*in.ih);
  float4 bb;
  bb.x = fminf(fmaxf(gx - gw*0.5f, 0.0f), Wi);
  bb.y = fminf(fmaxf(gy - gh*0.5f, 0.0f), Hi);
  bb.z = fminf(fmaxf(gx + gw*0.5f, 0.0f), Wi);
  bb.w = fminf(fmaxf(gy + gh*0.5f, 0.0f), Hi);
  ((float4*)sel_box)[img*MTOT + pos] = bb;
}

// ---- K6: NMS suppression-mask build — 256-row x 4-word tiles ----
// Row per lane; column boxes staged in 4KB LDS (broadcast reads, no conflicts).
// IoU decision WITHOUT the IEEE div in 99.999% of cases; rare ambiguous lanes
// take the exact f32 division. IoU on OFFSET boxes (+lvl*4096) bit-matches ref.
__global__ void __launch_bounds__(256) k_masks(const float* __restrict__ sel_box,
                        unsigned long long* __restrict__ maskbuf) {
  int pair = blockIdx.y; int lvl = pair % NLVL; int img = pair / NLVL;
  int n = KSEL[lvl];
  int nw = (n + 63) >> 6;
  int rblk = blockIdx.x >> 3;          // 0..7 (row tile of 256)
  int wg   = blockIdx.x & 7;           // 0..7 (word group of 4)
  int row0 = rblk * 256;
  int w0 = wg * 4, w1 = w0 + 4;
  if (row0 >= n) return;               // block-uniform exits (before barrier)
  if (w0 >= nw) return;
  if (w1 <= (row0 >> 6)) return;       // tile fully below diagonal
  __shared__ float4 bx[256];           // this tile's column boxes
  const float4* boxes = ((const float4*)sel_box) + img*MTOT + SOFF[lvl];
  float off = (float)lvl * 4096.0f;
  {
    int j = w0*64 + threadIdx.x;
    if (j < n) {
      float4 b = boxes[j];
      b.x += off; b.y += off; b.z += off; b.w += off;
      bx[threadIdx.x] = b;
    }
  }
  __syncthreads();
  int i = row0 + threadIdx.x;          // row per lane
  bool act = (i < n);
  float4 bi = make_float4(0.f, 0.f, 0.f, 0.f);
  float ai = 0.f;
  if (act) {
    bi = boxes[i];
    bi.x += off; bi.y += off; bi.z += off; bi.w += off;
    ai = (bi.z - bi.x) * (bi.w - bi.y);
  }
  int ws = (row0 + (threadIdx.x & ~63)) >> 6;   // wave-uniform: == i>>6 for all lanes
  int jw_lo = max(w0, ws);
  int jw_hi = min(w1, nw);
  unsigned long long* mrow = maskbuf + (size_t)pair*2000*MASK_W + (size_t)i*MASK_W;
  for (int jw = jw_lo; jw < jw_hi; jw++) {
    int jbase = jw * 64;
    int lbase = (jw - w0) * 64;
    int bmax = min(64, n - jbase);
    unsigned long long wbits = 0ull;
    #pragma unroll 4
    for (int b = 0; b < bmax; b++) {
      float4 bj = bx[lbase + b];       // LDS broadcast (uniform address)
      float aj = (bj.z - bj.x) * (bj.w - bj.y);
      float xx1 = fmaxf(bi.x, bj.x), yy1 = fmaxf(bi.y, bj.y);
      float xx2 = fminf(bi.z, bj.z), yy2 = fminf(bi.w, bj.w);
      float iw_ = fmaxf(xx2 - xx1, 0.0f), ih_ = fmaxf(yy2 - yy1, 0.0f);
      float inter = iw_ * ih_;
      float uni = fmaxf(ai + aj - inter, 1e-6f);
      float prod = 0.7f * uni;
      float diff = inter - prod;
      bool sup;
      if (fabsf(diff) <= prod * 3.8e-6f) {
        sup = (inter / uni) > 0.7f;    // rare exact path (exec-masked, usually skipped)
      } else {
        sup = diff > 0.0f;
      }
      sup = sup && (jbase + b > i);
      wbits |= ((unsigned long long)sup) << b;
    }
    if (act) mrow[jw] = wbits;
  }
}

// ---- K7: block-diagonal greedy NMS (one wave per (img,lvl)) ----
// NO readlane on load results (that forced per-row serialization in r5-r11):
//  * diagonal 64 words come in via SCALAR loads (uniform address -> s_load into
//    SGPRs, 16-row chunks); the serial greedy chain is pure SALU on them.
//  * vector R[32] (word w of block rows) feeds ONLY the streaming accumulate
//    OR - standard batchable VMEM consumption, issued before the chain so the
//    chain shadows its latency. Only 2 readlane_u64/block remain (rem -> S0).
__global__ void __launch_bounds__(64, 1) k_nms(const unsigned long long* __restrict__ maskbuf,
                      unsigned long long* __restrict__ keep) {
  int pair = blockIdx.x; int lvl = pair % NLVL;
  int n = KSEL[lvl];
  int nw = (n + 63) >> 6;
  int lane = threadIdx.x;
  int w = lane & 31;                   // word index this lane owns
  int h = lane >> 5;                   // row-half: rows h*32..h*32+31 of each block
  const unsigned long long* mrow = maskbuf + (size_t)pair*2000*MASK_W;
  unsigned long long rem = 0ull;       // lane (w,h): suppression word w from rows half h
  unsigned long long frozen = ~0ull;   // final suppressed mask for word w (set at k==w)
  unsigned long long R[32];

  for (int k = 0; k < nw; k++) {
    int rbase = 64*k + h*32;
    int nb = n - 64*k; if (nb > 64) nb = 64;   // valid boxes in this block
    // ---- vector loads: word w of this block's rows (unconditional, clamped).
    //      Consumed ONLY by the accumulate below -> batchable; the SALU chain
    //      between issue and use shadows the memory latency.
    #pragma unroll
    for (int i = 0; i < 32; i++) {
      int row = rbase + i;
      if (row > n - 1) row = n - 1;    // clamp: always a valid written row
      R[i] = mrow[(size_t)row*MASK_W + w];
    }
    // ---- serial greedy chain on SGPRs: diagonal words via uniform (scalar)
    //      loads in 4 chunks of 16 rows (32 SGPRs per chunk).
    unsigned long long S = readlane_u64(rem, k) | readlane_u64(rem, k + 32);
    #pragma unroll
    for (int c = 0; c < 4; c++) {
      unsigned long long M[16];
      #pragma unroll
      for (int i = 0; i < 16; i++) {
        int row = 64*k + c*16 + i;
        if (row > n - 1) row = n - 1;  // clamped row's word k is written (row>>6==k region)
        M[i] = mrow[(size_t)row*MASK_W + k];   // uniform address -> s_load
      }
      #pragma unroll
      for (int i = 0; i < 16; i++) {
        int b = c*16 + i;
        unsigned long long m = (b < nb) ? M[i] : 0ull;
        S |= ((S >> b) & 1ull) ? 0ull : m;     // pure SALU, b constexpr
      }
    }
    if (lane == k) frozen = S;
    // ---- streaming accumulate: alive rows' suppression into later words ----
    if (w > k) {
      unsigned Sh = (unsigned)(h ? (S >> 32) : S);   // per-lane half of S
      unsigned long long r0 = 0ull, r1 = 0ull;       // 2 accumulators for ILP
      #pragma unroll
      for (int i = 0; i < 32; i += 2) {
        bool a0 = (rbase + i     < n) && !((Sh >> i)       & 1u);
        bool a1 = (rbase + i + 1 < n) && !((Sh >> (i + 1)) & 1u);
        r0 |= a0 ? R[i]     : 0ull;
        r1 |= a1 ? R[i + 1] : 0ull;
      }
      rem |= r0 | r1;
    }
  }
  if (lane < MASK_W)
    keep[(size_t)pair*MASK_W + lane] = ~frozen;
}

// ---- K7b: inclusive prefix-count of kept per (img,lvl) position ----
__global__ void __launch_bounds__(64) k_pfx(const unsigned long long* __restrict__ keep,
                                            int* __restrict__ pkc) {
  int pair = blockIdx.x; int lvl = pair % NLVL;
  int n = KSEL[lvl];
  int nw = (n + 63) >> 6;
  int lane = threadIdx.x;
  unsigned long long w = (lane < nw) ? keep[(size_t)pair*MASK_W + lane] : 0ull;
  if (lane == nw - 1 && (n & 63)) w &= (1ull << (n & 63)) - 1ull;  // bits >= n are garbage
  __shared__ int lcnt[64];
  lcnt[lane] = __popcll(w);
  __syncthreads();
  int pre = 0;
  for (int t = 0; t < lane; t++) pre += lcnt[t];   // <=63 LDS adds, one wave — fine
  for (int b = 0; b < 64; b++) {
    int p = lane*64 + b;
    if (p < n) {
      pre += (int)((w >> b) & 1ull);
      pkc[pair*2048 + p] = pre;
    }
  }
}

// ---- K8: rank kept boxes via per-level prefix counts + 4 binary searches ----
__global__ void __launch_bounds__(256) k_out2(const unsigned long long* __restrict__ sel_key,
                      const float* __restrict__ sel_box,
                      const unsigned long long* __restrict__ keep,
                      const int* __restrict__ pkc,
                      float* __restrict__ out) {
  int img = blockIdx.y;
  int pos = blockIdx.x*256 + threadIdx.x;
  if (pos >= MTOT) return;
  int lvl = pos<2000?0 : pos<4000?1 : pos<6000?2 : pos<8000?3 : 4;
  int local = pos - SOFF[lvl];
  int pair = img*NLVL + lvl;
  unsigned long long kw = keep[(size_t)pair*MASK_W + (local >> 6)];
  if (!((kw >> (local & 63)) & 1ull)) return;
  unsigned long long mykey = sel_key[img*MTOT + pos];
  int rank = pkc[pair*2048 + local] - 1;    // kept before me within my level
  #pragma unroll
  for (int l2 = 0; l2 < NLVL; l2++) {
    if (l2 == lvl) continue;
    const unsigned long long* A = sel_key + img*MTOT + SOFF[l2];
    int lo = 0, hi = KSEL[l2];
    while (lo < hi) {
      int mid = (lo + hi) >> 1;
      if (A[mid] > mykey) lo = mid + 1; else hi = mid;
    }
    if (lo > 0) rank += pkc[(img*NLVL + l2)*2048 + lo - 1];
  }
  if (rank < OUTK) {
    ((float4*)out)[img*OUTK + rank] = ((const float4*)sel_box)[img*MTOT + pos];
    out[NIMG*OUTK*4 + img*OUTK + rank] = __uint_as_float((unsigned)(mykey >> 21));
  }
}

extern "C" void kernel_launch(void* const* d_in, const int* in_sizes, int n_in,
                              void* d_out, int out_size, void* d_ws, size_t ws_size,
                              hipStream_t stream) {
  Ins in;
  // setup_inputs dict order: cls_0, reg_0, cls_1, reg_1, ..., cls_4, reg_4, image_h, image_w
  for (int l = 0; l < 5; l++) {
    in.cls[l] = (const float*)d_in[2*l];
    in.reg[l] = (const float*)d_in[2*l + 1];
  }
  in.ih = (const int*)d_in[10];
  in.iw = (const int*)d_in[11];

  char* ws = (char*)d_ws;
  unsigned* hist              = (unsigned*)(ws + OFF_HIST);
  int* pkc                    = (int*)(ws + OFF_PKC);          // aliases hist (dead after k_scan)
  unsigned* cnt               = (unsigned*)(ws + OFF_CNT);
  unsigned* thr               = (unsigned*)(ws + OFF_THR);
  unsigned* cand              = (unsigned*)(ws + OFF_CAND);
  unsigned* sel_idx           = (unsigned*)(ws + OFF_SELIDX);
  unsigned long long* sel_key = (unsigned long long*)(ws + OFF_SELKEY);
  float* sel_sc               = (float*)(ws + OFF_SELSC);
  float* sel_box              = (float*)(ws + OFF_SELBOX);
  unsigned long long* maskbuf = (unsigned long long*)(ws + OFF_MASK);
  unsigned long long* ckey    = (unsigned long long*)(ws + OFF_CKEY);  // aliases maskbuf (dead before k_masks)
  unsigned long long* keep    = (unsigned long long*)(ws + OFF_KEEP);
  float* out                  = (float*)d_out;

  hipMemsetAsync(d_ws, 0, ZERO_BYTES, stream);                 // hist + counters + thr
  hipMemsetAsync(d_out, 0, (size_t)NIMG*OUTK*5*sizeof(float), stream); // zero-padded outputs

  k_hist   <<<NIMG*BLK_PER_IMG, 256, 0, stream>>>(in, hist);
  k_scan   <<<NPAIR, 256, 0, stream>>>(hist, thr);
  k_compact<<<NIMG*BLK_PER_IMG, 256, 0, stream>>>(in, thr, cnt, cand);
  k_keys   <<<dim3(CAP/256, NPAIR), 256, 0, stream>>>(in, cnt, cand, ckey);
  k_rank   <<<dim3(CAP/256, NPAIR), 256, 0, stream>>>(cnt, cand, ckey, sel_idx, sel_key, sel_sc);
  k_decode <<<(NIMG*MTOT + 255)/256, 256, 0, stream>>>(in, sel_idx, sel_box);
  k_masks  <<<dim3(64, NPAIR), 256, 0, stream>>>(sel_box, maskbuf);
  k_nms    <<<NPAIR, 64, 0, stream>>>(maskbuf, keep);
  k_pfx    <<<NPAIR, 64, 0, stream>>>(keep, pkc);
  k_out2   <<<dim3((MTOT + 255)/256, NIMG), 256, 0, stream>>>(sel_key, sel_box, keep, pkc, out);
}

// Round 13
// 389.966 us; speedup vs baseline: 1.2015x; 1.2015x over previous
//
#include <hip/hip_runtime.h>
#include <cmath>

// Match XLA/numpy non-fused mul+add rounding everywhere (IoU / decode bit-faithfulness).
#pragma clang fp contract(off)

namespace {
constexpr int NIMG = 8;
constexpr int NLVL = 5;
constexpr int LH[5]   = {208,104,52,26,13};
constexpr int LW[5]   = {336,168,84,42,21};
constexpr int LSTR[5] = {4,8,16,32,64};
constexpr int HWA[5]  = {209664,52416,13104,3276,819};
constexpr int KSEL[5] = {2000,2000,2000,2000,819};
constexpr int SOFF[5] = {0,2000,4000,6000,8000};
constexpr int MTOT    = 8819;
constexpr int CAP     = 6144;          // per-(img,lvl) candidate cap (expect <= ~2600)
constexpr int NPAIR   = NIMG*NLVL;     // 40
constexpr int CCUM[5] = {52,65,69,70,71};  // cumulative ceil(HWA/4096) per level
constexpr int BLK_PER_IMG = 71;
constexpr int MASK_W  = 32;            // u64 words per NMS mask row (covers 2048 cols)
constexpr int OUTK    = 1000;

// workspace byte offsets (all 16B-aligned where needed)
constexpr size_t OFF_HIST   = 0;              // 40*4096*4      = 655360
constexpr size_t OFF_PKC    = 0;              // 40*2048*4 = 327680, aliases hist (dead after k_scan)
constexpr size_t OFF_CNT    = 655360;         // 40*4           = 160
constexpr size_t OFF_THR    = 655520;         // 40*4           = 160
constexpr size_t ZERO_BYTES = 655680;         // memset range (hist+cnt+thr)
constexpr size_t OFF_CAND   = 655872;         // 40*6144*4      = 983040  -> 1638912
constexpr size_t OFF_SELIDX = 1638912;        // 8*8819*4       = 282208  -> 1921120
constexpr size_t OFF_SELKEY = 1921120;        // 8*8819*8       = 564416  -> 2485536
constexpr size_t OFF_SELSC  = 2485536;        // 8*8819*4       = 282208  -> 2767744
constexpr size_t OFF_SELBOX = 2767744;        // 8*8819*16      = 1128832 -> 3896576
constexpr size_t OFF_MASK   = 3896576;        // 40*2000*32*8   = 20480000-> 24376576
constexpr size_t OFF_CKEY   = OFF_MASK;       // 40*6144*8 = 1.97MB aliases maskbuf (dead by k_masks)
constexpr size_t OFF_KEEP   = 24376576;       // 40*32*8        = 10240   -> 24386816
}

struct Ins {
  const float* cls[5];
  const float* reg[5];
  const int* ih;
  const int* iw;
};

__device__ __forceinline__ void decode_block(int b, int& img, int& lvl, int& chunk) {
  img = b / BLK_PER_IMG;
  int rb = b - img*BLK_PER_IMG;
  if      (rb < CCUM[0]) { lvl=0; chunk=rb; }
  else if (rb < CCUM[1]) { lvl=1; chunk=rb-CCUM[0]; }
  else if (rb < CCUM[2]) { lvl=2; chunk=rb-CCUM[1]; }
  else if (rb < CCUM[3]) { lvl=3; chunk=rb-CCUM[2]; }
  else                   { lvl=4; chunk=0; }
}

// order-preserving float->u32 map (total order over floats)
__device__ __forceinline__ unsigned mapbits(float x) {
  unsigned u = __float_as_uint(x);
  return u ^ (unsigned)(((int)u >> 31) | (int)0x80000000);
}

// fp32 sigmoid with correctly-rounded exp step: matches 1/(1+exp_f32(-x)) pipeline
__device__ __forceinline__ float sigmoid_ref(float x) {
  float e = (float)exp(-(double)x);   // correctly-rounded f32 exp(-x)
  return 1.0f / (1.0f + e);           // exact-IEEE add + div
}

// ---- K1: per-(img,lvl) 12-bit histogram of mapped logit bits ----
__global__ void k_hist(Ins in, unsigned* __restrict__ hist) {
  int img, lvl, chunk; decode_block(blockIdx.x, img, lvl, chunk);
  __shared__ unsigned lh[4096];
  for (int i = threadIdx.x; i < 4096; i += 256) lh[i] = 0;
  __syncthreads();
  const float* src = in.cls[lvl] + (size_t)img * HWA[lvl];
  int base = chunk * 4096;
  #pragma unroll
  for (int j = 0; j < 16; j++) {
    int e = base + j*256 + threadIdx.x;
    if (e < HWA[lvl]) {
      unsigned m = mapbits(src[e]);
      atomicAdd(&lh[m >> 20], 1u);
    }
  }
  __syncthreads();
  unsigned* gh = hist + (img*NLVL + lvl) * 4096;
  for (int i = threadIdx.x; i < 4096; i += 256)
    if (lh[i]) atomicAdd(&gh[i], lh[i]);
}

// ---- K2: find highest bin-edge with suffix count >= k ----
__global__ void k_scan(const unsigned* __restrict__ hist, unsigned* __restrict__ thr) {
  int pair = blockIdx.x; int lvl = pair % NLVL;
  const unsigned* h = hist + (size_t)pair * 4096;
  __shared__ unsigned part[256];
  unsigned s = 0;
  #pragma unroll
  for (int i = 0; i < 16; i++) s += h[threadIdx.x*16 + i];
  part[threadIdx.x] = s;
  __syncthreads();
  if (threadIdx.x == 0) {
    unsigned k = (unsigned)KSEL[lvl];
    unsigned cum = 0;
    unsigned edge = 0;
    for (int t = 255; t >= 0; t--) {
      if (cum + part[t] >= k) {
        for (int b = t*16 + 15; b >= t*16; b--) {
          cum += h[b];
          if (cum >= k) { edge = (unsigned)b; break; }
        }
        thr[pair] = edge << 20;
        return;
      }
      cum += part[t];
    }
    thr[pair] = 0u;
  }
}

// ---- K3: compact candidates; LDS block aggregation -> ONE global atomic/block ----
__global__ void __launch_bounds__(256) k_compact(Ins in, const unsigned* __restrict__ thr,
                          unsigned* __restrict__ cnt, unsigned* __restrict__ cand) {
  int img, lvl, chunk; decode_block(blockIdx.x, img, lvl, chunk);
  int pair = img*NLVL + lvl;
  unsigned T = thr[pair];
  const float* src = in.cls[lvl] + (size_t)img * HWA[lvl];
  int hw = LH[lvl] * LW[lvl];
  int base = chunk * 4096;
  int lid = threadIdx.x & 63;
  __shared__ unsigned lbuf[4096];      // block covers <=4096 elements: p always fits
  __shared__ unsigned lc, gbase;
  if (threadIdx.x == 0) lc = 0;
  __syncthreads();
  #pragma unroll
  for (int j = 0; j < 16; j++) {
    int e = base + j*256 + threadIdx.x;
    bool sel = (e < HWA[lvl]) && (mapbits(src[e]) >= T);
    unsigned long long mask = __ballot(sel);
    if (mask != 0ull) {
      int leader = __ffsll((long long)mask) - 1;
      unsigned wb = 0;
      if (lid == leader) wb = atomicAdd(&lc, (unsigned)__popcll(mask));  // LDS atomic
      wb = (unsigned)__shfl((int)wb, leader, 64);
      if (sel) {
        unsigned p = wb + (unsigned)__popcll(mask & ((1ull << lid) - 1ull));
        int a = e / hw;            // NCHW: e = a*hw + r
        int r = e - a*hw;
        lbuf[p] = (unsigned)(r*3 + a);  // score-space idx
      }
    }
  }
  __syncthreads();
  if (threadIdx.x == 0) gbase = atomicAdd(&cnt[pair], lc);  // one global atomic/block
  __syncthreads();
  unsigned nsel = lc, gb = gbase;
  for (unsigned t = threadIdx.x; t < nsel; t += 256) {
    unsigned p = gb + t;
    if (p < CAP) cand[(size_t)pair*CAP + p] = lbuf[t];      // coalesced
  }
}

// ---- K3b: compute sort keys ONCE per candidate (hoists dp-exp out of k_rank tiles) ----
__global__ void k_keys(Ins in, const unsigned* __restrict__ cntA,
                       const unsigned* __restrict__ cand,
                       unsigned long long* __restrict__ ckey) {
  int pair = blockIdx.y;
  int img = pair / NLVL, lvl = pair % NLVL;
  int c = min((int)cntA[pair], CAP);
  int j = blockIdx.x*256 + threadIdx.x;
  if (j >= c) return;
  unsigned idx = cand[(size_t)pair*CAP + j];
  int a = (int)(idx % 3u), r = (int)(idx / 3u);
  int hw = LH[lvl]*LW[lvl];
  float s = sigmoid_ref(in.cls[lvl][(size_t)img*HWA[lvl] + a*hw + r]);
  unsigned pack = ((unsigned)lvl << 18) | idx;   // < 2^21
  ckey[(size_t)pair*CAP + j] = ((unsigned long long)__float_as_uint(s) << 21)
                             | (unsigned long long)(0x1FFFFFu - pack);  // desc score, asc (lvl,idx)
}

// ---- K4: per-level exact rank (score desc, idx asc); scatter top-k into slots ----
__global__ void __launch_bounds__(256) k_rank(const unsigned* __restrict__ cntA,
                       const unsigned* __restrict__ cand,
                       const unsigned long long* __restrict__ ckey,
                       unsigned* __restrict__ sel_idx,
                       unsigned long long* __restrict__ sel_key,
                       float* __restrict__ sel_sc) {
  int pair = blockIdx.y; int tile = blockIdx.x;
  int img = pair / NLVL, lvl = pair % NLVL;
  int c = min((int)cntA[pair], CAP);
  if (tile*256 >= c) return;
  __shared__ unsigned long long keys[CAP];
  const unsigned long long* kp = ckey + (size_t)pair*CAP;
  for (int j = threadIdx.x; j < c; j += 256) keys[j] = kp[j];
  __syncthreads();
  int jj = tile*256 + threadIdx.x;
  if (jj >= c) return;
  unsigned long long mykey = keys[jj];
  int rk = 0;
  for (int j = 0; j < c; j++) rk += (keys[j] > mykey) ? 1 : 0;  // LDS broadcast
  if (rk < KSEL[lvl]) {
    int slot = img*MTOT + SOFF[lvl] + rk;
    sel_idx[slot] = cand[(size_t)pair*CAP + jj];
    sel_key[slot] = mykey;
    sel_sc[slot]  = __uint_as_float((unsigned)(mykey >> 21));
  }
}

// ---- K5: decode boxes (exact mmdet DeltaXYWH replication, clipped) ----
__global__ void k_decode(Ins in, const unsigned* __restrict__ sel_idx,
                         float* __restrict__ sel_box) {
  int t = blockIdx.x*256 + threadIdx.x;
  if (t >= NIMG*MTOT) return;
  int img = t / MTOT, pos = t - img*MTOT;
  int lvl = pos<2000?0 : pos<4000?1 : pos<6000?2 : pos<8000?3 : 4;
  unsigned idx = sel_idx[img*MTOT + pos];
  int a = (int)(idx % 3u);
  int r = (int)(idx / 3u);
  int Wl = LW[lvl]; int hw = LH[lvl]*Wl;
  int x = r % Wl, y = r / Wl;
  const float* rg = in.reg[lvl] + (size_t)img * 4 * HWA[lvl];  // 12*H*W
  float dx = rg[(a*4+0)*hw + r];
  float dy = rg[(a*4+1)*hw + r];
  float dw = rg[(a*4+2)*hw + r];
  float dh = rg[(a*4+3)*hw + r];
  float ratio = (a==0) ? 0.5f : (a==1) ? 1.0f : 2.0f;
  float hr = sqrtf(ratio);
  float wr = 1.0f / hr;
  float st = (float)LSTR[lvl];
  float wsz = st * wr * 8.0f;
  float hsz = st * hr * 8.0f;
  float xs = (float)x * st, ys = (float)y * st;
  float x1 = xs - wsz*0.5f, x2 = xs + wsz*0.5f;
  float y1 = ys - hsz*0.5f, y2 = ys + hsz*0.5f;
  float px = (x1 + x2) * 0.5f, py = (y1 + y2) * 0.5f;
  float pw = x2 - x1,          ph = y2 - y1;
  const float MR = 4.135166556742356f;
  dw = fminf(fmaxf(dw, -MR), MR);
  dh = fminf(fmaxf(dh, -MR), MR);
  float gx = px + pw*dx, gy = py + ph*dy;
  float gw = pw * (float)exp((double)dw);   // correctly-rounded f32 exp
  float gh = ph * (float)exp((double)dh);
  float Wi = (float)(*in.iw), Hi = (float)(*in.ih);
  float4 bb;
  bb.x = fminf(fmaxf(gx - gw*0.5f, 0.0f), Wi);
  bb.y = fminf(fmaxf(gy - gh*0.5f, 0.0f), Hi);
  bb.z = fminf(fmaxf(gx + gw*0.5f, 0.0f), Wi);
  bb.w = fminf(fmaxf(gy + gh*0.5f, 0.0f), Hi);
  ((float4*)sel_box)[img*MTOT + pos] = bb;
}

// ---- K6: NMS suppression-mask build — 256-row x 4-word tiles ----
// Row per lane; column boxes staged in 4KB LDS (broadcast reads, no conflicts).
// IoU decision WITHOUT the IEEE div in 99.999% of cases; rare ambiguous lanes
// take the exact f32 division. IoU on OFFSET boxes (+lvl*4096) bit-matches ref.
__global__ void __launch_bounds__(256) k_masks(const float* __restrict__ sel_box,
                        unsigned long long* __restrict__ maskbuf) {
  int pair = blockIdx.y; int lvl = pair % NLVL; int img = pair / NLVL;
  int n = KSEL[lvl];
  int nw = (n + 63) >> 6;
  int rblk = blockIdx.x >> 3;          // 0..7 (row tile of 256)
  int wg   = blockIdx.x & 7;           // 0..7 (word group of 4)
  int row0 = rblk * 256;
  int w0 = wg * 4, w1 = w0 + 4;
  if (row0 >= n) return;               // block-uniform exits (before barrier)
  if (w0 >= nw) return;
  if (w1 <= (row0 >> 6)) return;       // tile fully below diagonal
  __shared__ float4 bx[256];           // this tile's column boxes
  const float4* boxes = ((const float4*)sel_box) + img*MTOT + SOFF[lvl];
  float off = (float)lvl * 4096.0f;
  {
    int j = w0*64 + threadIdx.x;
    if (j < n) {
      float4 b = boxes[j];
      b.x += off; b.y += off; b.z += off; b.w += off;
      bx[threadIdx.x] = b;
    }
  }
  __syncthreads();
  int i = row0 + threadIdx.x;          // row per lane
  bool act = (i < n);
  float4 bi = make_float4(0.f, 0.f, 0.f, 0.f);
  float ai = 0.f;
  if (act) {
    bi = boxes[i];
    bi.x += off; bi.y += off; bi.z += off; bi.w += off;
    ai = (bi.z - bi.x) * (bi.w - bi.y);
  }
  int ws = (row0 + (threadIdx.x & ~63)) >> 6;   // wave-uniform: == i>>6 for all lanes
  int jw_lo = max(w0, ws);
  int jw_hi = min(w1, nw);
  unsigned long long* mrow = maskbuf + (size_t)pair*2000*MASK_W + (size_t)i*MASK_W;
  for (int jw = jw_lo; jw < jw_hi; jw++) {
    int jbase = jw * 64;
    int lbase = (jw - w0) * 64;
    int bmax = min(64, n - jbase);
    unsigned long long wbits = 0ull;
    #pragma unroll 4
    for (int b = 0; b < bmax; b++) {
      float4 bj = bx[lbase + b];       // LDS broadcast (uniform address)
      float aj = (bj.z - bj.x) * (bj.w - bj.y);
      float xx1 = fmaxf(bi.x, bj.x), yy1 = fmaxf(bi.y, bj.y);
      float xx2 = fminf(bi.z, bj.z), yy2 = fminf(bi.w, bj.w);
      float iw_ = fmaxf(xx2 - xx1, 0.0f), ih_ = fmaxf(yy2 - yy1, 0.0f);
      float inter = iw_ * ih_;
      float uni = fmaxf(ai + aj - inter, 1e-6f);
      float prod = 0.7f * uni;
      float diff = inter - prod;
      bool sup;
      if (fabsf(diff) <= prod * 3.8e-6f) {
        sup = (inter / uni) > 0.7f;    // rare exact path (exec-masked, usually skipped)
      } else {
        sup = diff > 0.0f;
      }
      sup = sup && (jbase + b > i);
      wbits |= ((unsigned long long)sup) << b;
    }
    if (act) mrow[jw] = wbits;
  }
}

// ---- K7: greedy NMS as a Jacobi FIXPOINT (one 1024-thread block per pair) ----
// keep[i] = !OR_{j<i, keep[j]} sup[j][i] is strictly lower-triangular -> unique
// fixpoint == greedy result; Jacobi iteration converges in (chain depth)+1
// rounds. Each round is a fully PARALLEL streaming OR over kept rows' mask
// words (16 waves; lanes 0-31 read a row's words contiguously = coalesced
// 256B; sparse nonzero words atomicOr into 32-word LDS ssup). No serial
// load-consume chain -> latency hidden by TLP, not compiler prefetch.
__global__ void __launch_bounds__(1024) k_nms(const unsigned long long* __restrict__ maskbuf,
                      unsigned long long* __restrict__ keep) {
  int pair = blockIdx.x; int lvl = pair % NLVL;
  int n = KSEL[lvl];
  int nw = (n + 63) >> 6;
  const unsigned long long* mrow = maskbuf + (size_t)pair*2000*MASK_W;
  __shared__ unsigned long long skeep[32], ssup[32];
  __shared__ int changed;
  int tid = threadIdx.x;
  int wv = tid >> 6, lane = tid & 63;
  int w = lane & 31;                   // word this lane reads within a row
  int half = lane >> 5;                // 0: even row of pass, 1: odd row
  if (tid < 32) skeep[tid] = ~0ull;    // start: all kept
  __syncthreads();
  for (;;) {
    if (tid < 32) ssup[tid] = 0ull;
    if (tid == 0) changed = 0;
    __syncthreads();
    // rows: 16 waves x 2 rows per pass -> stride 32
    for (int r = wv*2 + half; r < n; r += 32) {
      bool kept = (skeep[r >> 6] >> (r & 63)) & 1ull;
      if (kept && w >= (r >> 6) && w < nw) {
        unsigned long long m = mrow[(size_t)r*MASK_W + w];   // coalesced 256B/row
        if (m) atomicOr(&ssup[w], m);                        // sparse
      }
    }
    __syncthreads();
    if (tid < 32) {
      unsigned long long nk = ~ssup[tid];
      if (tid == nw - 1 && (n & 63)) nk &= (1ull << (n & 63)) - 1ull;
      if (tid >= nw) nk = skeep[tid];  // untouched tail words: no false change
      if (nk != skeep[tid]) { changed = 1; skeep[tid] = nk; }
    }
    __syncthreads();
    bool done = (changed == 0);
    __syncthreads();                   // protect 'changed' reset next iter
    if (done) break;
  }
  if (tid < 32) keep[(size_t)pair*MASK_W + tid] = skeep[tid];
}

// ---- K7b: inclusive prefix-count of kept per (img,lvl) position ----
__global__ void __launch_bounds__(64) k_pfx(const unsigned long long* __restrict__ keep,
                                            int* __restrict__ pkc) {
  int pair = blockIdx.x; int lvl = pair % NLVL;
  int n = KSEL[lvl];
  int nw = (n + 63) >> 6;
  int lane = threadIdx.x;
  unsigned long long w = (lane < nw) ? keep[(size_t)pair*MASK_W + lane] : 0ull;
  if (lane == nw - 1 && (n & 63)) w &= (1ull << (n & 63)) - 1ull;  // bits >= n are garbage
  __shared__ int lcnt[64];
  lcnt[lane] = __popcll(w);
  __syncthreads();
  int pre = 0;
  for (int t = 0; t < lane; t++) pre += lcnt[t];   // <=63 LDS adds, one wave — fine
  for (int b = 0; b < 64; b++) {
    int p = lane*64 + b;
    if (p < n) {
      pre += (int)((w >> b) & 1ull);
      pkc[pair*2048 + p] = pre;
    }
  }
}

// ---- K8: rank kept boxes via per-level prefix counts + 4 binary searches ----
__global__ void __launch_bounds__(256) k_out2(const unsigned long long* __restrict__ sel_key,
                      const float* __restrict__ sel_box,
                      const unsigned long long* __restrict__ keep,
                      const int* __restrict__ pkc,
                      float* __restrict__ out) {
  int img = blockIdx.y;
  int pos = blockIdx.x*256 + threadIdx.x;
  if (pos >= MTOT) return;
  int lvl = pos<2000?0 : pos<4000?1 : pos<6000?2 : pos<8000?3 : 4;
  int local = pos - SOFF[lvl];
  int pair = img*NLVL + lvl;
  unsigned long long kw = keep[(size_t)pair*MASK_W + (local >> 6)];
  if (!((kw >> (local & 63)) & 1ull)) return;
  unsigned long long mykey = sel_key[img*MTOT + pos];
  int rank = pkc[pair*2048 + local] - 1;    // kept before me within my level
  #pragma unroll
  for (int l2 = 0; l2 < NLVL; l2++) {
    if (l2 == lvl) continue;
    const unsigned long long* A = sel_key + img*MTOT + SOFF[l2];
    int lo = 0, hi = KSEL[l2];
    while (lo < hi) {
      int mid = (lo + hi) >> 1;
      if (A[mid] > mykey) lo = mid + 1; else hi = mid;
    }
    if (lo > 0) rank += pkc[(img*NLVL + l2)*2048 + lo - 1];
  }
  if (rank < OUTK) {
    ((float4*)out)[img*OUTK + rank] = ((const float4*)sel_box)[img*MTOT + pos];
    out[NIMG*OUTK*4 + img*OUTK + rank] = __uint_as_float((unsigned)(mykey >> 21));
  }
}

extern "C" void kernel_launch(void* const* d_in, const int* in_sizes, int n_in,
                              void* d_out, int out_size, void* d_ws, size_t ws_size,
                              hipStream_t stream) {
  Ins in;
  // setup_inputs dict order: cls_0, reg_0, cls_1, reg_1, ..., cls_4, reg_4, image_h, image_w
  for (int l = 0; l < 5; l++) {
    in.cls[l] = (const float*)d_in[2*l];
    in.reg[l] = (const float*)d_in[2*l + 1];
  }
  in.ih = (const int*)d_in[10];
  in.iw = (const int*)d_in[11];

  char* ws = (char*)d_ws;
  unsigned* hist              = (unsigned*)(ws + OFF_HIST);
  int* pkc                    = (int*)(ws + OFF_PKC);          // aliases hist (dead after k_scan)
  unsigned* cnt               = (unsigned*)(ws + OFF_CNT);
  unsigned* thr               = (unsigned*)(ws + OFF_THR);
  unsigned* cand              = (unsigned*)(ws + OFF_CAND);
  unsigned* sel_idx           = (unsigned*)(ws + OFF_SELIDX);
  unsigned long long* sel_key = (unsigned long long*)(ws + OFF_SELKEY);
  float* sel_sc               = (float*)(ws + OFF_SELSC);
  float* sel_box              = (float*)(ws + OFF_SELBOX);
  unsigned long long* maskbuf = (unsigned long long*)(ws + OFF_MASK);
  unsigned long long* ckey    = (unsigned long long*)(ws + OFF_CKEY);  // aliases maskbuf (dead before k_masks)
  unsigned long long* keep    = (unsigned long long*)(ws + OFF_KEEP);
  float* out                  = (float*)d_out;

  hipMemsetAsync(d_ws, 0, ZERO_BYTES, stream);                 // hist + counters + thr
  hipMemsetAsync(d_out, 0, (size_t)NIMG*OUTK*5*sizeof(float), stream); // zero-padded outputs

  k_hist   <<<NIMG*BLK_PER_IMG, 256, 0, stream>>>(in, hist);
  k_scan   <<<NPAIR, 256, 0, stream>>>(hist, thr);
  k_compact<<<NIMG*BLK_PER_IMG, 256, 0, stream>>>(in, thr, cnt, cand);
  k_keys   <<<dim3(CAP/256, NPAIR), 256, 0, stream>>>(in, cnt, cand, ckey);
  k_rank   <<<dim3(CAP/256, NPAIR), 256, 0, stream>>>(cnt, cand, ckey, sel_idx, sel_key, sel_sc);
  k_decode <<<(NIMG*MTOT + 255)/256, 256, 0, stream>>>(in, sel_idx, sel_box);
  k_masks  <<<dim3(64, NPAIR), 256, 0, stream>>>(sel_box, maskbuf);
  k_nms    <<<NPAIR, 1024, 0, stream>>>(maskbuf, keep);
  k_pfx    <<<NPAIR, 64, 0, stream>>>(keep, pkc);
  k_out2   <<<dim3((MTOT + 255)/256, NIMG), 256, 0, stream>>>(sel_key, sel_box, keep, pkc, out);
}

// Round 14
// 348.698 us; speedup vs baseline: 1.3437x; 1.1183x over previous
//
#include <hip/hip_runtime.h>
#include <cmath>

// Match XLA/numpy non-fused mul+add rounding everywhere (IoU / decode bit-faithfulness).
#pragma clang fp contract(off)

namespace {
constexpr int NIMG = 8;
constexpr int NLVL = 5;
constexpr int LH[5]   = {208,104,52,26,13};
constexpr int LW[5]   = {336,168,84,42,21};
constexpr int LSTR[5] = {4,8,16,32,64};
constexpr int HWA[5]  = {209664,52416,13104,3276,819};
constexpr int KSEL[5] = {2000,2000,2000,2000,819};
constexpr int SOFF[5] = {0,2000,4000,6000,8000};
constexpr int MTOT    = 8819;
constexpr int CAP     = 6144;          // per-(img,lvl) candidate cap (expect <= ~2600)
constexpr int NPAIR   = NIMG*NLVL;     // 40
constexpr int CCUM[5] = {52,65,69,70,71};  // cumulative ceil(HWA/4096) per level
constexpr int BLK_PER_IMG = 71;
constexpr int MASK_W  = 32;            // u64 words per NMS mask row (covers 2048 cols)
constexpr int OUTK    = 1000;

// workspace byte offsets (all 16B-aligned where needed)
constexpr size_t OFF_HIST   = 0;              // 40*4096*4      = 655360
constexpr size_t OFF_PKC    = 0;              // 40*2048*4 = 327680, aliases hist (dead after k_scan)
constexpr size_t OFF_CNT    = 655360;         // 40*4           = 160
constexpr size_t OFF_THR    = 655520;         // 40*4           = 160
constexpr size_t ZERO_BYTES = 655680;         // memset range (hist+cnt+thr)
constexpr size_t OFF_CAND   = 655872;         // 40*6144*4      = 983040  -> 1638912
constexpr size_t OFF_SELIDX = 1638912;        // 8*8819*4       = 282208  -> 1921120
constexpr size_t OFF_SELKEY = 1921120;        // 8*8819*8       = 564416  -> 2485536
constexpr size_t OFF_SELSC  = 2485536;        // 8*8819*4       = 282208  -> 2767744
constexpr size_t OFF_SELBOX = 2767744;        // 8*8819*16      = 1128832 -> 3896576
constexpr size_t OFF_MASK   = 3896576;        // 40*2000*32*8   = 20480000-> 24376576
constexpr size_t OFF_CKEY   = OFF_MASK;       // 40*6144*8 = 1.97MB aliases maskbuf (dead by k_masks)
constexpr size_t OFF_KEEP   = 24376576;       // 40*32*8        = 10240   -> 24386816
}

struct Ins {
  const float* cls[5];
  const float* reg[5];
  const int* ih;
  const int* iw;
};

__device__ __forceinline__ void decode_block(int b, int& img, int& lvl, int& chunk) {
  img = b / BLK_PER_IMG;
  int rb = b - img*BLK_PER_IMG;
  if      (rb < CCUM[0]) { lvl=0; chunk=rb; }
  else if (rb < CCUM[1]) { lvl=1; chunk=rb-CCUM[0]; }
  else if (rb < CCUM[2]) { lvl=2; chunk=rb-CCUM[1]; }
  else if (rb < CCUM[3]) { lvl=3; chunk=rb-CCUM[2]; }
  else                   { lvl=4; chunk=0; }
}

// order-preserving float->u32 map (total order over floats)
__device__ __forceinline__ unsigned mapbits(float x) {
  unsigned u = __float_as_uint(x);
  return u ^ (unsigned)(((int)u >> 31) | (int)0x80000000);
}

// fp32 sigmoid with correctly-rounded exp step: matches 1/(1+exp_f32(-x)) pipeline
__device__ __forceinline__ float sigmoid_ref(float x) {
  float e = (float)exp(-(double)x);   // correctly-rounded f32 exp(-x)
  return 1.0f / (1.0f + e);           // exact-IEEE add + div
}

// ---- K1: per-(img,lvl) 12-bit histogram of mapped logit bits ----
__global__ void k_hist(Ins in, unsigned* __restrict__ hist) {
  int img, lvl, chunk; decode_block(blockIdx.x, img, lvl, chunk);
  __shared__ unsigned lh[4096];
  for (int i = threadIdx.x; i < 4096; i += 256) lh[i] = 0;
  __syncthreads();
  const float* src = in.cls[lvl] + (size_t)img * HWA[lvl];
  int base = chunk * 4096;
  #pragma unroll
  for (int j = 0; j < 16; j++) {
    int e = base + j*256 + threadIdx.x;
    if (e < HWA[lvl]) {
      unsigned m = mapbits(src[e]);
      atomicAdd(&lh[m >> 20], 1u);
    }
  }
  __syncthreads();
  unsigned* gh = hist + (img*NLVL + lvl) * 4096;
  for (int i = threadIdx.x; i < 4096; i += 256)
    if (lh[i]) atomicAdd(&gh[i], lh[i]);
}

// ---- K2: find highest bin-edge with suffix count >= k ----
__global__ void k_scan(const unsigned* __restrict__ hist, unsigned* __restrict__ thr) {
  int pair = blockIdx.x; int lvl = pair % NLVL;
  const unsigned* h = hist + (size_t)pair * 4096;
  __shared__ unsigned part[256];
  unsigned s = 0;
  #pragma unroll
  for (int i = 0; i < 16; i++) s += h[threadIdx.x*16 + i];
  part[threadIdx.x] = s;
  __syncthreads();
  if (threadIdx.x == 0) {
    unsigned k = (unsigned)KSEL[lvl];
    unsigned cum = 0;
    unsigned edge = 0;
    for (int t = 255; t >= 0; t--) {
      if (cum + part[t] >= k) {
        for (int b = t*16 + 15; b >= t*16; b--) {
          cum += h[b];
          if (cum >= k) { edge = (unsigned)b; break; }
        }
        thr[pair] = edge << 20;
        return;
      }
      cum += part[t];
    }
    thr[pair] = 0u;
  }
}

// ---- K3: compact candidates; LDS block aggregation -> ONE global atomic/block ----
__global__ void __launch_bounds__(256) k_compact(Ins in, const unsigned* __restrict__ thr,
                          unsigned* __restrict__ cnt, unsigned* __restrict__ cand) {
  int img, lvl, chunk; decode_block(blockIdx.x, img, lvl, chunk);
  int pair = img*NLVL + lvl;
  unsigned T = thr[pair];
  const float* src = in.cls[lvl] + (size_t)img * HWA[lvl];
  int hw = LH[lvl] * LW[lvl];
  int base = chunk * 4096;
  int lid = threadIdx.x & 63;
  __shared__ unsigned lbuf[4096];      // block covers <=4096 elements: p always fits
  __shared__ unsigned lc, gbase;
  if (threadIdx.x == 0) lc = 0;
  __syncthreads();
  #pragma unroll
  for (int j = 0; j < 16; j++) {
    int e = base + j*256 + threadIdx.x;
    bool sel = (e < HWA[lvl]) && (mapbits(src[e]) >= T);
    unsigned long long mask = __ballot(sel);
    if (mask != 0ull) {
      int leader = __ffsll((long long)mask) - 1;
      unsigned wb = 0;
      if (lid == leader) wb = atomicAdd(&lc, (unsigned)__popcll(mask));  // LDS atomic
      wb = (unsigned)__shfl((int)wb, leader, 64);
      if (sel) {
        unsigned p = wb + (unsigned)__popcll(mask & ((1ull << lid) - 1ull));
        int a = e / hw;            // NCHW: e = a*hw + r
        int r = e - a*hw;
        lbuf[p] = (unsigned)(r*3 + a);  // score-space idx
      }
    }
  }
  __syncthreads();
  if (threadIdx.x == 0) gbase = atomicAdd(&cnt[pair], lc);  // one global atomic/block
  __syncthreads();
  unsigned nsel = lc, gb = gbase;
  for (unsigned t = threadIdx.x; t < nsel; t += 256) {
    unsigned p = gb + t;
    if (p < CAP) cand[(size_t)pair*CAP + p] = lbuf[t];      // coalesced
  }
}

// ---- K3b: compute sort keys ONCE per candidate (hoists dp-exp out of k_rank tiles) ----
__global__ void k_keys(Ins in, const unsigned* __restrict__ cntA,
                       const unsigned* __restrict__ cand,
                       unsigned long long* __restrict__ ckey) {
  int pair = blockIdx.y;
  int img = pair / NLVL, lvl = pair % NLVL;
  int c = min((int)cntA[pair], CAP);
  int j = blockIdx.x*256 + threadIdx.x;
  if (j >= c) return;
  unsigned idx = cand[(size_t)pair*CAP + j];
  int a = (int)(idx % 3u), r = (int)(idx / 3u);
  int hw = LH[lvl]*LW[lvl];
  float s = sigmoid_ref(in.cls[lvl][(size_t)img*HWA[lvl] + a*hw + r]);
  unsigned pack = ((unsigned)lvl << 18) | idx;   // < 2^21
  ckey[(size_t)pair*CAP + j] = ((unsigned long long)__float_as_uint(s) << 21)
                             | (unsigned long long)(0x1FFFFFu - pack);  // desc score, asc (lvl,idx)
}

// ---- K4: per-level exact rank (score desc, idx asc); scatter top-k into slots ----
__global__ void __launch_bounds__(256) k_rank(const unsigned* __restrict__ cntA,
                       const unsigned* __restrict__ cand,
                       const unsigned long long* __restrict__ ckey,
                       unsigned* __restrict__ sel_idx,
                       unsigned long long* __restrict__ sel_key,
                       float* __restrict__ sel_sc) {
  int pair = blockIdx.y; int tile = blockIdx.x;
  int img = pair / NLVL, lvl = pair % NLVL;
  int c = min((int)cntA[pair], CAP);
  if (tile*256 >= c) return;
  __shared__ unsigned long long keys[CAP];
  const unsigned long long* kp = ckey + (size_t)pair*CAP;
  for (int j = threadIdx.x; j < c; j += 256) keys[j] = kp[j];
  __syncthreads();
  int jj = tile*256 + threadIdx.x;
  if (jj >= c) return;
  unsigned long long mykey = keys[jj];
  int rk = 0;
  for (int j = 0; j < c; j++) rk += (keys[j] > mykey) ? 1 : 0;  // LDS broadcast
  if (rk < KSEL[lvl]) {
    int slot = img*MTOT + SOFF[lvl] + rk;
    sel_idx[slot] = cand[(size_t)pair*CAP + jj];
    sel_key[slot] = mykey;
    sel_sc[slot]  = __uint_as_float((unsigned)(mykey >> 21));
  }
}

// ---- K5: decode boxes (exact mmdet DeltaXYWH replication, clipped) ----
__global__ void k_decode(Ins in, const unsigned* __restrict__ sel_idx,
                         float* __restrict__ sel_box) {
  int t = blockIdx.x*256 + threadIdx.x;
  if (t >= NIMG*MTOT) return;
  int img = t / MTOT, pos = t - img*MTOT;
  int lvl = pos<2000?0 : pos<4000?1 : pos<6000?2 : pos<8000?3 : 4;
  unsigned idx = sel_idx[img*MTOT + pos];
  int a = (int)(idx % 3u);
  int r = (int)(idx / 3u);
  int Wl = LW[lvl]; int hw = LH[lvl]*Wl;
  int x = r % Wl, y = r / Wl;
  const float* rg = in.reg[lvl] + (size_t)img * 4 * HWA[lvl];  // 12*H*W
  float dx = rg[(a*4+0)*hw + r];
  float dy = rg[(a*4+1)*hw + r];
  float dw = rg[(a*4+2)*hw + r];
  float dh = rg[(a*4+3)*hw + r];
  float ratio = (a==0) ? 0.5f : (a==1) ? 1.0f : 2.0f;
  float hr = sqrtf(ratio);
  float wr = 1.0f / hr;
  float st = (float)LSTR[lvl];
  float wsz = st * wr * 8.0f;
  float hsz = st * hr * 8.0f;
  float xs = (float)x * st, ys = (float)y * st;
  float x1 = xs - wsz*0.5f, x2 = xs + wsz*0.5f;
  float y1 = ys - hsz*0.5f, y2 = ys + hsz*0.5f;
  float px = (x1 + x2) * 0.5f, py = (y1 + y2) * 0.5f;
  float pw = x2 - x1,          ph = y2 - y1;
  const float MR = 4.135166556742356f;
  dw = fminf(fmaxf(dw, -MR), MR);
  dh = fminf(fmaxf(dh, -MR), MR);
  float gx = px + pw*dx, gy = py + ph*dy;
  float gw = pw * (float)exp((double)dw);   // correctly-rounded f32 exp
  float gh = ph * (float)exp((double)dh);
  float Wi = (float)(*in.iw), Hi = (float)(*in.ih);
  float4 bb;
  bb.x = fminf(fmaxf(gx - gw*0.5f, 0.0f), Wi);
  bb.y = fminf(fmaxf(gy - gh*0.5f, 0.0f), Hi);
  bb.z = fminf(fmaxf(gx + gw*0.5f, 0.0f), Wi);
  bb.w = fminf(fmaxf(gy + gh*0.5f, 0.0f), Hi);
  ((float4*)sel_box)[img*MTOT + pos] = bb;
}

// ---- K6: NMS suppression-mask build — ballot tiles, 64 cols x 64 rows/wave ----
// Lane = column: bj + area live in REGISTERS (loaded once per tile, no per-b
// LDS read). Rows broadcast from a wave-private LDS stage (no __syncthreads;
// waves retire independently -> uniform ~1.4us tiles, tight packing).
// Bit-exact IoU>0.7 via diff = rn(1.7*inter) - rn(0.7*rn(ai+aj)) == algebra on
// the SAME rounded t=ai+aj the reference uses; margin 6.5e-6*(s+p) >> rounding
// uncertainty; rare ambiguous lanes take the exact max(t-inter,1e-6) division.
// IoU on OFFSET boxes (+lvl*4096) bit-matches reference batched NMS.
// Writes exactly words [i>>6, nw) per row, matching k_nms's predicated reads.
__global__ void __launch_bounds__(256) k_masks(const float* __restrict__ sel_box,
                        unsigned long long* __restrict__ maskbuf) {
  int pair = blockIdx.y; int lvl = pair % NLVL; int img = pair / NLVL;
  int n = KSEL[lvl];
  int nw = (n + 63) >> 6;
  int wv = threadIdx.x >> 6;
  int lane = threadIdx.x & 63;
  int t = blockIdx.x * 4 + wv;           // flat triangular tile id
  int ntile = nw * (nw + 1) / 2;
  if (t >= ntile) return;                // wave-level exit (no barriers used)
  int rb = 0, cum = 0;
  while (cum + (nw - rb) <= t) { cum += nw - rb; rb++; }
  int jw = rb + (t - cum);               // word strip; jw >= rb (upper-tri)
  const float4* boxes = ((const float4*)sel_box) + img*MTOT + SOFF[lvl];
  float off = (float)lvl * 4096.0f;
  // columns: this lane's box in registers
  int col = jw*64 + lane;
  float4 bj = boxes[min(col, n-1)];
  float bjx = bj.x + off, bjy = bj.y + off, bjz = bj.z + off, bjww = bj.w + off;
  float aj = (bjz - bjx) * (bjww - bjy);
  // rows: stage this wave's 64 row boxes + areas (wave-private LDS segment)
  __shared__ float4 srow[4][64];
  __shared__ float  sarea[4][64];
  int row0 = rb*64;
  float4 bi0 = boxes[min(row0 + lane, n-1)];
  bi0.x += off; bi0.y += off; bi0.z += off; bi0.w += off;
  srow[wv][lane] = bi0;
  sarea[wv][lane] = (bi0.z - bi0.x) * (bi0.w - bi0.y);
  // (wave-synchronous LDS: compiler inserts lgkmcnt wait before reads)
  unsigned long long colmask = ~0ull;
  if (jw == nw-1 && (n & 63)) colmask = (1ull << (n & 63)) - 1ull;
  unsigned long long acc = 0ull;
  #pragma unroll 4
  for (int r = 0; r < 64; r++) {
    float4 bi = srow[wv][r];             // LDS broadcast (uniform address)
    float ai = sarea[wv][r];
    float xx1 = fmaxf(bi.x, bjx), yy1 = fmaxf(bi.y, bjy);
    float xx2 = fminf(bi.z, bjz), yy2 = fminf(bi.w, bjww);
    float iw_ = fmaxf(xx2 - xx1, 0.0f), ih_ = fmaxf(yy2 - yy1, 0.0f);
    float inter = iw_ * ih_;
    float tt = ai + aj;                  // same rounded sum as reference
    float s = 1.7f * inter;
    float p = 0.7f * tt;
    float diff = s - p;                  // == inter - 0.7*(tt - inter) exactly
    float m = 6.5e-6f * (s + p);
    bool amb = fabsf(diff) <= m;
    bool sup = diff > 0.0f;
    if (__any(amb)) {
      if (amb) {                         // rare exact path (exec-masked)
        float uni = fmaxf(tt - inter, 1e-6f);
        sup = (inter / uni) > 0.7f;
      }
    }
    unsigned long long word = __ballot(sup) & colmask;
    if (jw == rb) word &= ~((2ull << r) - 1ull);   // j > i on the diagonal
    if (lane == r) acc = word;
  }
  // one store per tile: rows row0..row0+63 at word jw (rows >= n unread)
  maskbuf[(size_t)pair*2000*MASK_W + (size_t)(row0 + lane)*MASK_W + jw] = acc;
}

// ---- K7: greedy NMS as a Jacobi FIXPOINT (one 1024-thread block per pair) ----
// keep[i] = !OR_{j<i, keep[j]} sup[j][i] is strictly lower-triangular -> unique
// fixpoint == greedy result; Jacobi iteration converges in (chain depth)+1
// rounds. Each round is a fully PARALLEL streaming OR over kept rows' mask
// words (16 waves; lanes 0-31 read a row's words contiguously = coalesced
// 256B; sparse nonzero words atomicOr into 32-word LDS ssup). No serial
// load-consume chain -> latency hidden by TLP, not compiler prefetch.
__global__ void __launch_bounds__(1024) k_nms(const unsigned long long* __restrict__ maskbuf,
                      unsigned long long* __restrict__ keep) {
  int pair = blockIdx.x; int lvl = pair % NLVL;
  int n = KSEL[lvl];
  int nw = (n + 63) >> 6;
  const unsigned long long* mrow = maskbuf + (size_t)pair*2000*MASK_W;
  __shared__ unsigned long long skeep[32], ssup[32];
  __shared__ int changed;
  int tid = threadIdx.x;
  int wv = tid >> 6, lane = tid & 63;
  int w = lane & 31;                   // word this lane reads within a row
  int half = lane >> 5;                // 0: even row of pass, 1: odd row
  if (tid < 32) skeep[tid] = ~0ull;    // start: all kept
  __syncthreads();
  for (;;) {
    if (tid < 32) ssup[tid] = 0ull;
    if (tid == 0) changed = 0;
    __syncthreads();
    // rows: 16 waves x 2 rows per pass -> stride 32
    for (int r = wv*2 + half; r < n; r += 32) {
      bool kept = (skeep[r >> 6] >> (r & 63)) & 1ull;
      if (kept && w >= (r >> 6) && w < nw) {
        unsigned long long m = mrow[(size_t)r*MASK_W + w];   // coalesced 256B/row
        if (m) atomicOr(&ssup[w], m);                        // sparse
      }
    }
    __syncthreads();
    if (tid < 32) {
      unsigned long long nk = ~ssup[tid];
      if (tid == nw - 1 && (n & 63)) nk &= (1ull << (n & 63)) - 1ull;
      if (tid >= nw) nk = skeep[tid];  // untouched tail words: no false change
      if (nk != skeep[tid]) { changed = 1; skeep[tid] = nk; }
    }
    __syncthreads();
    bool done = (changed == 0);
    __syncthreads();                   // protect 'changed' reset next iter
    if (done) break;
  }
  if (tid < 32) keep[(size_t)pair*MASK_W + tid] = skeep[tid];
}

// ---- K7b: inclusive prefix-count of kept per (img,lvl) position ----
__global__ void __launch_bounds__(64) k_pfx(const unsigned long long* __restrict__ keep,
                                            int* __restrict__ pkc) {
  int pair = blockIdx.x; int lvl = pair % NLVL;
  int n = KSEL[lvl];
  int nw = (n + 63) >> 6;
  int lane = threadIdx.x;
  unsigned long long w = (lane < nw) ? keep[(size_t)pair*MASK_W + lane] : 0ull;
  if (lane == nw - 1 && (n & 63)) w &= (1ull << (n & 63)) - 1ull;  // bits >= n are garbage
  __shared__ int lcnt[64];
  lcnt[lane] = __popcll(w);
  __syncthreads();
  int pre = 0;
  for (int t = 0; t < lane; t++) pre += lcnt[t];   // <=63 LDS adds, one wave — fine
  for (int b = 0; b < 64; b++) {
    int p = lane*64 + b;
    if (p < n) {
      pre += (int)((w >> b) & 1ull);
      pkc[pair*2048 + p] = pre;
    }
  }
}

// ---- K8: rank kept boxes via per-level prefix counts + 4 binary searches ----
__global__ void __launch_bounds__(256) k_out2(const unsigned long long* __restrict__ sel_key,
                      const float* __restrict__ sel_box,
                      const unsigned long long* __restrict__ keep,
                      const int* __restrict__ pkc,
                      float* __restrict__ out) {
  int img = blockIdx.y;
  int pos = blockIdx.x*256 + threadIdx.x;
  if (pos >= MTOT) return;
  int lvl = pos<2000?0 : pos<4000?1 : pos<6000?2 : pos<8000?3 : 4;
  int local = pos - SOFF[lvl];
  int pair = img*NLVL + lvl;
  unsigned long long kw = keep[(size_t)pair*MASK_W + (local >> 6)];
  if (!((kw >> (local & 63)) & 1ull)) return;
  unsigned long long mykey = sel_key[img*MTOT + pos];
  int rank = pkc[pair*2048 + local] - 1;    // kept before me within my level
  #pragma unroll
  for (int l2 = 0; l2 < NLVL; l2++) {
    if (l2 == lvl) continue;
    const unsigned long long* A = sel_key + img*MTOT + SOFF[l2];
    int lo = 0, hi = KSEL[l2];
    while (lo < hi) {
      int mid = (lo + hi) >> 1;
      if (A[mid] > mykey) lo = mid + 1; else hi = mid;
    }
    if (lo > 0) rank += pkc[(img*NLVL + l2)*2048 + lo - 1];
  }
  if (rank < OUTK) {
    ((float4*)out)[img*OUTK + rank] = ((const float4*)sel_box)[img*MTOT + pos];
    out[NIMG*OUTK*4 + img*OUTK + rank] = __uint_as_float((unsigned)(mykey >> 21));
  }
}

extern "C" void kernel_launch(void* const* d_in, const int* in_sizes, int n_in,
                              void* d_out, int out_size, void* d_ws, size_t ws_size,
                              hipStream_t stream) {
  Ins in;
  // setup_inputs dict order: cls_0, reg_0, cls_1, reg_1, ..., cls_4, reg_4, image_h, image_w
  for (int l = 0; l < 5; l++) {
    in.cls[l] = (const float*)d_in[2*l];
    in.reg[l] = (const float*)d_in[2*l + 1];
  }
  in.ih = (const int*)d_in[10];
  in.iw = (const int*)d_in[11];

  char* ws = (char*)d_ws;
  unsigned* hist              = (unsigned*)(ws + OFF_HIST);
  int* pkc                    = (int*)(ws + OFF_PKC);          // aliases hist (dead after k_scan)
  unsigned* cnt               = (unsigned*)(ws + OFF_CNT);
  unsigned* thr               = (unsigned*)(ws + OFF_THR);
  unsigned* cand              = (unsigned*)(ws + OFF_CAND);
  unsigned* sel_idx           = (unsigned*)(ws + OFF_SELIDX);
  unsigned long long* sel_key = (unsigned long long*)(ws + OFF_SELKEY);
  float* sel_sc               = (float*)(ws + OFF_SELSC);
  float* sel_box              = (float*)(ws + OFF_SELBOX);
  unsigned long long* maskbuf = (unsigned long long*)(ws + OFF_MASK);
  unsigned long long* ckey    = (unsigned long long*)(ws + OFF_CKEY);  // aliases maskbuf (dead before k_masks)
  unsigned long long* keep    = (unsigned long long*)(ws + OFF_KEEP);
  float* out                  = (float*)d_out;

  hipMemsetAsync(d_ws, 0, ZERO_BYTES, stream);                 // hist + counters + thr
  hipMemsetAsync(d_out, 0, (size_t)NIMG*OUTK*5*sizeof(float), stream); // zero-padded outputs

  k_hist   <<<NIMG*BLK_PER_IMG, 256, 0, stream>>>(in, hist);
  k_scan   <<<NPAIR, 256, 0, stream>>>(hist, thr);
  k_compact<<<NIMG*BLK_PER_IMG, 256, 0, stream>>>(in, thr, cnt, cand);
  k_keys   <<<dim3(CAP/256, NPAIR), 256, 0, stream>>>(in, cnt, cand, ckey);
  k_rank   <<<dim3(CAP/256, NPAIR), 256, 0, stream>>>(cnt, cand, ckey, sel_idx, sel_key, sel_sc);
  k_decode <<<(NIMG*MTOT + 255)/256, 256, 0, stream>>>(in, sel_idx, sel_box);
  k_masks  <<<dim3(132, NPAIR), 256, 0, stream>>>(sel_box, maskbuf);
  k_nms    <<<NPAIR, 1024, 0, stream>>>(maskbuf, keep);
  k_pfx    <<<NPAIR, 64, 0, stream>>>(keep, pkc);
  k_out2   <<<dim3((MTOT + 255)/256, NIMG), 256, 0, stream>>>(sel_key, sel_box, keep, pkc, out);
}

// Round 15
// 292.791 us; speedup vs baseline: 1.6002x; 1.1909x over previous
//
#include <hip/hip_runtime.h>
#include <cmath>

// Match XLA/numpy non-fused mul+add rounding everywhere (IoU / decode bit-faithfulness).
#pragma clang fp contract(off)

namespace {
constexpr int NIMG = 8;
constexpr int NLVL = 5;
constexpr int LH[5]   = {208,104,52,26,13};
constexpr int LW[5]   = {336,168,84,42,21};
constexpr int LSTR[5] = {4,8,16,32,64};
constexpr int HWA[5]  = {209664,52416,13104,3276,819};
constexpr int KSEL[5] = {2000,2000,2000,2000,819};
constexpr int SOFF[5] = {0,2000,4000,6000,8000};
constexpr int MTOT    = 8819;
constexpr int CAP     = 6144;          // per-(img,lvl) candidate cap (expect <= ~2600)
constexpr int NPAIR   = NIMG*NLVL;     // 40
constexpr int CCUM[5] = {52,65,69,70,71};  // cumulative ceil(HWA/4096) per level
constexpr int BLK_PER_IMG = 71;
constexpr int MASK_W  = 32;            // u64 words per NMS mask row (covers 2048 cols)
constexpr int OUTK    = 1000;

// workspace byte offsets (all 16B-aligned where needed)
constexpr size_t OFF_HIST   = 0;              // 40*4096*4      = 655360
constexpr size_t OFF_PKC    = 0;              // 40*2048*4 = 327680, aliases hist (dead after k_scan)
constexpr size_t OFF_CNT    = 655360;         // 40*4           = 160
constexpr size_t OFF_THR    = 655520;         // 40*4           = 160
constexpr size_t ZERO_BYTES = 655680;         // memset range (hist+cnt+thr)
constexpr size_t OFF_CAND   = 655872;         // 40*6144*4      = 983040  -> 1638912
constexpr size_t OFF_SELIDX = 1638912;        // 8*8819*4       = 282208  -> 1921120
constexpr size_t OFF_SELKEY = 1921120;        // 8*8819*8       = 564416  -> 2485536
constexpr size_t OFF_SELSC  = 2485536;        // 8*8819*4       = 282208  -> 2767744
constexpr size_t OFF_SELBOX = 2767744;        // 8*8819*16      = 1128832 -> 3896576
constexpr size_t OFF_MASK   = 3896576;        // 40*2000*32*8   = 20480000-> 24376576
constexpr size_t OFF_CKEY   = OFF_MASK;       // 40*6144*8 = 1.97MB aliases maskbuf (dead by k_masks)
constexpr size_t OFF_KEEP   = 24376576;       // 40*32*8        = 10240   -> 24386816
}

struct Ins {
  const float* cls[5];
  const float* reg[5];
  const int* ih;
  const int* iw;
};

__device__ __forceinline__ void decode_block(int b, int& img, int& lvl, int& chunk) {
  img = b / BLK_PER_IMG;
  int rb = b - img*BLK_PER_IMG;
  if      (rb < CCUM[0]) { lvl=0; chunk=rb; }
  else if (rb < CCUM[1]) { lvl=1; chunk=rb-CCUM[0]; }
  else if (rb < CCUM[2]) { lvl=2; chunk=rb-CCUM[1]; }
  else if (rb < CCUM[3]) { lvl=3; chunk=rb-CCUM[2]; }
  else                   { lvl=4; chunk=0; }
}

// order-preserving float->u32 map (total order over floats)
__device__ __forceinline__ unsigned mapbits(float x) {
  unsigned u = __float_as_uint(x);
  return u ^ (unsigned)(((int)u >> 31) | (int)0x80000000);
}

// fp32 sigmoid with correctly-rounded exp step: matches 1/(1+exp_f32(-x)) pipeline
__device__ __forceinline__ float sigmoid_ref(float x) {
  float e = (float)exp(-(double)x);   // correctly-rounded f32 exp(-x)
  return 1.0f / (1.0f + e);           // exact-IEEE add + div
}

// ---- K1: per-(img,lvl) 12-bit histogram of mapped logit bits ----
__global__ void k_hist(Ins in, unsigned* __restrict__ hist) {
  int img, lvl, chunk; decode_block(blockIdx.x, img, lvl, chunk);
  __shared__ unsigned lh[4096];
  for (int i = threadIdx.x; i < 4096; i += 256) lh[i] = 0;
  __syncthreads();
  const float* src = in.cls[lvl] + (size_t)img * HWA[lvl];
  int base = chunk * 4096;
  #pragma unroll
  for (int j = 0; j < 16; j++) {
    int e = base + j*256 + threadIdx.x;
    if (e < HWA[lvl]) {
      unsigned m = mapbits(src[e]);
      atomicAdd(&lh[m >> 20], 1u);
    }
  }
  __syncthreads();
  unsigned* gh = hist + (img*NLVL + lvl) * 4096;
  for (int i = threadIdx.x; i < 4096; i += 256)
    if (lh[i]) atomicAdd(&gh[i], lh[i]);
}

// ---- K2: find highest bin-edge with suffix count >= k ----
__global__ void k_scan(const unsigned* __restrict__ hist, unsigned* __restrict__ thr) {
  int pair = blockIdx.x; int lvl = pair % NLVL;
  const unsigned* h = hist + (size_t)pair * 4096;
  __shared__ unsigned part[256];
  unsigned s = 0;
  #pragma unroll
  for (int i = 0; i < 16; i++) s += h[threadIdx.x*16 + i];
  part[threadIdx.x] = s;
  __syncthreads();
  if (threadIdx.x == 0) {
    unsigned k = (unsigned)KSEL[lvl];
    unsigned cum = 0;
    unsigned edge = 0;
    for (int t = 255; t >= 0; t--) {
      if (cum + part[t] >= k) {
        for (int b = t*16 + 15; b >= t*16; b--) {
          cum += h[b];
          if (cum >= k) { edge = (unsigned)b; break; }
        }
        thr[pair] = edge << 20;
        return;
      }
      cum += part[t];
    }
    thr[pair] = 0u;
  }
}

// ---- K3: compact candidates; LDS block aggregation -> ONE global atomic/block ----
__global__ void __launch_bounds__(256) k_compact(Ins in, const unsigned* __restrict__ thr,
                          unsigned* __restrict__ cnt, unsigned* __restrict__ cand) {
  int img, lvl, chunk; decode_block(blockIdx.x, img, lvl, chunk);
  int pair = img*NLVL + lvl;
  unsigned T = thr[pair];
  const float* src = in.cls[lvl] + (size_t)img * HWA[lvl];
  int hw = LH[lvl] * LW[lvl];
  int base = chunk * 4096;
  int lid = threadIdx.x & 63;
  __shared__ unsigned lbuf[4096];      // block covers <=4096 elements: p always fits
  __shared__ unsigned lc, gbase;
  if (threadIdx.x == 0) lc = 0;
  __syncthreads();
  #pragma unroll
  for (int j = 0; j < 16; j++) {
    int e = base + j*256 + threadIdx.x;
    bool sel = (e < HWA[lvl]) && (mapbits(src[e]) >= T);
    unsigned long long mask = __ballot(sel);
    if (mask != 0ull) {
      int leader = __ffsll((long long)mask) - 1;
      unsigned wb = 0;
      if (lid == leader) wb = atomicAdd(&lc, (unsigned)__popcll(mask));  // LDS atomic
      wb = (unsigned)__shfl((int)wb, leader, 64);
      if (sel) {
        unsigned p = wb + (unsigned)__popcll(mask & ((1ull << lid) - 1ull));
        int a = e / hw;            // NCHW: e = a*hw + r
        int r = e - a*hw;
        lbuf[p] = (unsigned)(r*3 + a);  // score-space idx
      }
    }
  }
  __syncthreads();
  if (threadIdx.x == 0) gbase = atomicAdd(&cnt[pair], lc);  // one global atomic/block
  __syncthreads();
  unsigned nsel = lc, gb = gbase;
  for (unsigned t = threadIdx.x; t < nsel; t += 256) {
    unsigned p = gb + t;
    if (p < CAP) cand[(size_t)pair*CAP + p] = lbuf[t];      // coalesced
  }
}

// ---- K3b: compute sort keys ONCE per candidate (hoists dp-exp out of k_rank tiles) ----
__global__ void k_keys(Ins in, const unsigned* __restrict__ cntA,
                       const unsigned* __restrict__ cand,
                       unsigned long long* __restrict__ ckey) {
  int pair = blockIdx.y;
  int img = pair / NLVL, lvl = pair % NLVL;
  int c = min((int)cntA[pair], CAP);
  int j = blockIdx.x*256 + threadIdx.x;
  if (j >= c) return;
  unsigned idx = cand[(size_t)pair*CAP + j];
  int a = (int)(idx % 3u), r = (int)(idx / 3u);
  int hw = LH[lvl]*LW[lvl];
  float s = sigmoid_ref(in.cls[lvl][(size_t)img*HWA[lvl] + a*hw + r]);
  unsigned pack = ((unsigned)lvl << 18) | idx;   // < 2^21
  ckey[(size_t)pair*CAP + j] = ((unsigned long long)__float_as_uint(s) << 21)
                             | (unsigned long long)(0x1FFFFFu - pack);  // desc score, asc (lvl,idx)
}

// ---- K4: per-level exact rank (score desc, idx asc); scatter top-k into slots ----
__global__ void __launch_bounds__(256) k_rank(const unsigned* __restrict__ cntA,
                       const unsigned* __restrict__ cand,
                       const unsigned long long* __restrict__ ckey,
                       unsigned* __restrict__ sel_idx,
                       unsigned long long* __restrict__ sel_key,
                       float* __restrict__ sel_sc) {
  int pair = blockIdx.y; int tile = blockIdx.x;
  int img = pair / NLVL, lvl = pair % NLVL;
  int c = min((int)cntA[pair], CAP);
  if (tile*256 >= c) return;
  __shared__ unsigned long long keys[CAP];
  const unsigned long long* kp = ckey + (size_t)pair*CAP;
  for (int j = threadIdx.x; j < c; j += 256) keys[j] = kp[j];
  __syncthreads();
  int jj = tile*256 + threadIdx.x;
  if (jj >= c) return;
  unsigned long long mykey = keys[jj];
  int rk = 0;
  for (int j = 0; j < c; j++) rk += (keys[j] > mykey) ? 1 : 0;  // LDS broadcast
  if (rk < KSEL[lvl]) {
    int slot = img*MTOT + SOFF[lvl] + rk;
    sel_idx[slot] = cand[(size_t)pair*CAP + jj];
    sel_key[slot] = mykey;
    sel_sc[slot]  = __uint_as_float((unsigned)(mykey >> 21));
  }
}

// ---- K5: decode boxes (exact mmdet DeltaXYWH replication, clipped) ----
__global__ void k_decode(Ins in, const unsigned* __restrict__ sel_idx,
                         float* __restrict__ sel_box) {
  int t = blockIdx.x*256 + threadIdx.x;
  if (t >= NIMG*MTOT) return;
  int img = t / MTOT, pos = t - img*MTOT;
  int lvl = pos<2000?0 : pos<4000?1 : pos<6000?2 : pos<8000?3 : 4;
  unsigned idx = sel_idx[img*MTOT + pos];
  int a = (int)(idx % 3u);
  int r = (int)(idx / 3u);
  int Wl = LW[lvl]; int hw = LH[lvl]*Wl;
  int x = r % Wl, y = r / Wl;
  const float* rg = in.reg[lvl] + (size_t)img * 4 * HWA[lvl];  // 12*H*W
  float dx = rg[(a*4+0)*hw + r];
  float dy = rg[(a*4+1)*hw + r];
  float dw = rg[(a*4+2)*hw + r];
  float dh = rg[(a*4+3)*hw + r];
  float ratio = (a==0) ? 0.5f : (a==1) ? 1.0f : 2.0f;
  float hr = sqrtf(ratio);
  float wr = 1.0f / hr;
  float st = (float)LSTR[lvl];
  float wsz = st * wr * 8.0f;
  float hsz = st * hr * 8.0f;
  float xs = (float)x * st, ys = (float)y * st;
  float x1 = xs - wsz*0.5f, x2 = xs + wsz*0.5f;
  float y1 = ys - hsz*0.5f, y2 = ys + hsz*0.5f;
  float px = (x1 + x2) * 0.5f, py = (y1 + y2) * 0.5f;
  float pw = x2 - x1,          ph = y2 - y1;
  const float MR = 4.135166556742356f;
  dw = fminf(fmaxf(dw, -MR), MR);
  dh = fminf(fmaxf(dh, -MR), MR);
  float gx = px + pw*dx, gy = py + ph*dy;
  float gw = pw * (float)exp((double)dw);   // correctly-rounded f32 exp
  float gh = ph * (float)exp((double)dh);
  float Wi = (float)(*in.iw), Hi = (float)(*in.ih);
  float4 bb;
  bb.x = fminf(fmaxf(gx - gw*0.5f, 0.0f), Wi);
  bb.y = fminf(fmaxf(gy - gh*0.5f, 0.0f), Hi);
  bb.z = fminf(fmaxf(gx + gw*0.5f, 0.0f), Wi);
  bb.w = fminf(fmaxf(gy + gh*0.5f, 0.0f), Hi);
  ((float4*)sel_box)[img*MTOT + pos] = bb;
}

// ---- K6: NMS suppression-mask build — ballot tiles, 64 cols x 64 rows/wave ----
// Lane = column: bj + area in registers; rows broadcast from wave-private LDS.
// Bit-exact IoU>0.7 via diff = rn(1.7*inter) - rn(0.7*rn(ai+aj)); ambiguous
// lanes take the exact division. Store guarded to rows < n (r14 had an
// unguarded spill into the next pair's rows — latent race, fixed here).
__global__ void __launch_bounds__(256) k_masks(const float* __restrict__ sel_box,
                        unsigned long long* __restrict__ maskbuf) {
  int pair = blockIdx.y; int lvl = pair % NLVL; int img = pair / NLVL;
  int n = KSEL[lvl];
  int nw = (n + 63) >> 6;
  int wv = threadIdx.x >> 6;
  int lane = threadIdx.x & 63;
  int t = blockIdx.x * 4 + wv;           // flat triangular tile id
  int ntile = nw * (nw + 1) / 2;
  if (t >= ntile) return;                // wave-level exit (no barriers used)
  int rb = 0, cum = 0;
  while (cum + (nw - rb) <= t) { cum += nw - rb; rb++; }
  int jw = rb + (t - cum);               // word strip; jw >= rb (upper-tri)
  const float4* boxes = ((const float4*)sel_box) + img*MTOT + SOFF[lvl];
  float off = (float)lvl * 4096.0f;
  // columns: this lane's box in registers
  int col = jw*64 + lane;
  float4 bj = boxes[min(col, n-1)];
  float bjx = bj.x + off, bjy = bj.y + off, bjz = bj.z + off, bjww = bj.w + off;
  float aj = (bjz - bjx) * (bjww - bjy);
  // rows: stage this wave's 64 row boxes + areas (wave-private LDS segment)
  __shared__ float4 srow[4][64];
  __shared__ float  sarea[4][64];
  int row0 = rb*64;
  float4 bi0 = boxes[min(row0 + lane, n-1)];
  bi0.x += off; bi0.y += off; bi0.z += off; bi0.w += off;
  srow[wv][lane] = bi0;
  sarea[wv][lane] = (bi0.z - bi0.x) * (bi0.w - bi0.y);
  // (wave-synchronous LDS: compiler inserts lgkmcnt wait before reads)
  unsigned long long colmask = ~0ull;
  if (jw == nw-1 && (n & 63)) colmask = (1ull << (n & 63)) - 1ull;
  unsigned long long acc = 0ull;
  #pragma unroll 4
  for (int r = 0; r < 64; r++) {
    float4 bi = srow[wv][r];             // LDS broadcast (uniform address)
    float ai = sarea[wv][r];
    float xx1 = fmaxf(bi.x, bjx), yy1 = fmaxf(bi.y, bjy);
    float xx2 = fminf(bi.z, bjz), yy2 = fminf(bi.w, bjww);
    float iw_ = fmaxf(xx2 - xx1, 0.0f), ih_ = fmaxf(yy2 - yy1, 0.0f);
    float inter = iw_ * ih_;
    float tt = ai + aj;                  // same rounded sum as reference
    float s = 1.7f * inter;
    float p = 0.7f * tt;
    float diff = s - p;                  // == inter - 0.7*(tt - inter) exactly
    float m = 6.5e-6f * (s + p);
    bool amb = fabsf(diff) <= m;
    bool sup = diff > 0.0f;
    if (__any(amb)) {
      if (amb) {                         // rare exact path (exec-masked)
        float uni = fmaxf(tt - inter, 1e-6f);
        sup = (inter / uni) > 0.7f;
      }
    }
    unsigned long long word = __ballot(sup) & colmask;
    if (jw == rb) word &= ~((2ull << r) - 1ull);   // j > i on the diagonal
    if (lane == r) acc = word;
  }
  // one store per tile row; GUARDED to rows < n (no cross-pair spill)
  if (row0 + lane < n)
    maskbuf[(size_t)pair*2000*MASK_W + (size_t)(row0 + lane)*MASK_W + jw] = acc;
}

// ---- K7: EXACT one-pass block-sequential greedy NMS (1024 threads per pair) ----
// Per 64-box block k: (1) all threads hold word w of 2 block rows in a register
// DOUBLE BUFFER (loads for k+1 issued a full block early; only 4 u64 live ->
// no spill/sink pressure); (2) wave 0 runs the in-block triangle as a register
// Jacobi with wave-OR butterflies (no memory, no readlane-on-pending-load);
// (3) alive rows' words atomicOr into 32-word LDS rem. 3 barriers/block.
__global__ void __launch_bounds__(1024) k_nms(const unsigned long long* __restrict__ maskbuf,
                      unsigned long long* __restrict__ keep) {
  int pair = blockIdx.x; int lvl = pair % NLVL;
  int n = KSEL[lvl];
  int nw = (n + 63) >> 6;
  const unsigned long long* mrow = maskbuf + (size_t)pair*2000*MASK_W;
  int tid = threadIdx.x;
  int w  = tid & 31;                 // word owned (0..31)
  int rg = tid >> 5;                 // row group (0..31): rows rg*2, rg*2+1
  __shared__ unsigned long long rem[32];   // suppression from finalized kept boxes
  __shared__ unsigned long long diag[64];  // word k of current block's rows
  __shared__ unsigned long long sSk;       // final suppressed mask of block k
  if (tid < 32) rem[tid] = 0ull;
  __syncthreads();

  unsigned long long A0, A1, B0, B1;
  {
    int r0 = min(rg*2, n-1), r1 = min(rg*2+1, n-1);
    A0 = mrow[(size_t)r0*MASK_W + w];
    A1 = mrow[(size_t)r1*MASK_W + w];
  }
  for (int k = 0; k < nw; k++) {
    if (k + 1 < nw) {                // prefetch block k+1 (consumed next iter)
      int r0 = min(64*(k+1) + rg*2, n-1), r1 = min(64*(k+1) + rg*2 + 1, n-1);
      B0 = mrow[(size_t)r0*MASK_W + w];
      B1 = mrow[(size_t)r1*MASK_W + w];
    }
    if (w == k) { diag[rg*2] = A0; diag[rg*2+1] = A1; }
    __syncthreads();
    if (tid < 64) {                  // wave 0: in-block register Jacobi
      int row = 64*k + tid;
      bool valid = row < n;
      unsigned long long D = valid ? diag[tid] : 0ull;   // already strictly upper
      unsigned long long rk = rem[k];
      unsigned long long S = rk;
      for (int it = 0; it < 64; it++) {
        bool kept = valid && !((S >> tid) & 1ull);
        unsigned long long c = kept ? D : 0ull;
        #pragma unroll
        for (int m = 1; m < 64; m <<= 1) {               // wave-wide OR
          unsigned lo = (unsigned)__shfl_xor((int)(unsigned)(c & 0xffffffffull), m, 64);
          unsigned hi = (unsigned)__shfl_xor((int)(unsigned)(c >> 32), m, 64);
          c |= ((unsigned long long)hi << 32) | (unsigned long long)lo;
        }
        unsigned long long Snew = rk | c;                // uniform across wave
        if (Snew == S) break;                            // fixpoint (<= depth iters)
        S = Snew;
      }
      if (tid == 0) {
        sSk = S;
        int nb = n - 64*k;
        unsigned long long vm = (nb >= 64) ? ~0ull : ((1ull << nb) - 1ull);
        keep[(size_t)pair*MASK_W + k] = (~S) & vm;
      }
    }
    __syncthreads();
    if (w > k) {                     // accumulate alive rows into later words
      unsigned long long Sk = sSk;
      int r0 = 64*k + rg*2, r1 = r0 + 1;
      unsigned long long m = 0ull;
      if (r0 < n && !((Sk >> (rg*2)) & 1ull))     m |= A0;
      if (r1 < n && !((Sk >> (rg*2+1)) & 1ull))   m |= A1;
      if (m) atomicOr(&rem[w], m);
    }
    __syncthreads();
    A0 = B0; A1 = B1;
  }
}

// ---- K7b: inclusive prefix-count of kept per (img,lvl) position ----
__global__ void __launch_bounds__(64) k_pfx(const unsigned long long* __restrict__ keep,
                                            int* __restrict__ pkc) {
  int pair = blockIdx.x; int lvl = pair % NLVL;
  int n = KSEL[lvl];
  int nw = (n + 63) >> 6;
  int lane = threadIdx.x;
  unsigned long long w = (lane < nw) ? keep[(size_t)pair*MASK_W + lane] : 0ull;
  if (lane == nw - 1 && (n & 63)) w &= (1ull << (n & 63)) - 1ull;  // bits >= n are garbage
  __shared__ int lcnt[64];
  lcnt[lane] = __popcll(w);
  __syncthreads();
  int pre = 0;
  for (int t = 0; t < lane; t++) pre += lcnt[t];   // <=63 LDS adds, one wave — fine
  for (int b = 0; b < 64; b++) {
    int p = lane*64 + b;
    if (p < n) {
      pre += (int)((w >> b) & 1ull);
      pkc[pair*2048 + p] = pre;
    }
  }
}

// ---- K8: rank kept boxes via per-level prefix counts + 4 binary searches ----
__global__ void __launch_bounds__(256) k_out2(const unsigned long long* __restrict__ sel_key,
                      const float* __restrict__ sel_box,
                      const unsigned long long* __restrict__ keep,
                      const int* __restrict__ pkc,
                      float* __restrict__ out) {
  int img = blockIdx.y;
  int pos = blockIdx.x*256 + threadIdx.x;
  if (pos >= MTOT) return;
  int lvl = pos<2000?0 : pos<4000?1 : pos<6000?2 : pos<8000?3 : 4;
  int local = pos - SOFF[lvl];
  int pair = img*NLVL + lvl;
  unsigned long long kw = keep[(size_t)pair*MASK_W + (local >> 6)];
  if (!((kw >> (local & 63)) & 1ull)) return;
  unsigned long long mykey = sel_key[img*MTOT + pos];
  int rank = pkc[pair*2048 + local] - 1;    // kept before me within my level
  #pragma unroll
  for (int l2 = 0; l2 < NLVL; l2++) {
    if (l2 == lvl) continue;
    const unsigned long long* A = sel_key + img*MTOT + SOFF[l2];
    int lo = 0, hi = KSEL[l2];
    while (lo < hi) {
      int mid = (lo + hi) >> 1;
      if (A[mid] > mykey) lo = mid + 1; else hi = mid;
    }
    if (lo > 0) rank += pkc[(img*NLVL + l2)*2048 + lo - 1];
  }
  if (rank < OUTK) {
    ((float4*)out)[img*OUTK + rank] = ((const float4*)sel_box)[img*MTOT + pos];
    out[NIMG*OUTK*4 + img*OUTK + rank] = __uint_as_float((unsigned)(mykey >> 21));
  }
}

extern "C" void kernel_launch(void* const* d_in, const int* in_sizes, int n_in,
                              void* d_out, int out_size, void* d_ws, size_t ws_size,
                              hipStream_t stream) {
  Ins in;
  // setup_inputs dict order: cls_0, reg_0, cls_1, reg_1, ..., cls_4, reg_4, image_h, image_w
  for (int l = 0; l < 5; l++) {
    in.cls[l] = (const float*)d_in[2*l];
    in.reg[l] = (const float*)d_in[2*l + 1];
  }
  in.ih = (const int*)d_in[10];
  in.iw = (const int*)d_in[11];

  char* ws = (char*)d_ws;
  unsigned* hist              = (unsigned*)(ws + OFF_HIST);
  int* pkc                    = (int*)(ws + OFF_PKC);          // aliases hist (dead after k_scan)
  unsigned* cnt               = (unsigned*)(ws + OFF_CNT);
  unsigned* thr               = (unsigned*)(ws + OFF_THR);
  unsigned* cand              = (unsigned*)(ws + OFF_CAND);
  unsigned* sel_idx           = (unsigned*)(ws + OFF_SELIDX);
  unsigned long long* sel_key = (unsigned long long*)(ws + OFF_SELKEY);
  float* sel_sc               = (float*)(ws + OFF_SELSC);
  float* sel_box              = (float*)(ws + OFF_SELBOX);
  unsigned long long* maskbuf = (unsigned long long*)(ws + OFF_MASK);
  unsigned long long* ckey    = (unsigned long long*)(ws + OFF_CKEY);  // aliases maskbuf (dead before k_masks)
  unsigned long long* keep    = (unsigned long long*)(ws + OFF_KEEP);
  float* out                  = (float*)d_out;

  hipMemsetAsync(d_ws, 0, ZERO_BYTES, stream);                 // hist + counters + thr
  hipMemsetAsync(d_out, 0, (size_t)NIMG*OUTK*5*sizeof(float), stream); // zero-padded outputs

  k_hist   <<<NIMG*BLK_PER_IMG, 256, 0, stream>>>(in, hist);
  k_scan   <<<NPAIR, 256, 0, stream>>>(hist, thr);
  k_compact<<<NIMG*BLK_PER_IMG, 256, 0, stream>>>(in, thr, cnt, cand);
  k_keys   <<<dim3(CAP/256, NPAIR), 256, 0, stream>>>(in, cnt, cand, ckey);
  k_rank   <<<dim3(CAP/256, NPAIR), 256, 0, stream>>>(cnt, cand, ckey, sel_idx, sel_key, sel_sc);
  k_decode <<<(NIMG*MTOT + 255)/256, 256, 0, stream>>>(in, sel_idx, sel_box);
  k_masks  <<<dim3(132, NPAIR), 256, 0, stream>>>(sel_box, maskbuf);
  k_nms    <<<NPAIR, 1024, 0, stream>>>(maskbuf, keep);
  k_pfx    <<<NPAIR, 64, 0, stream>>>(keep, pkc);
  k_out2   <<<dim3((MTOT + 255)/256, NIMG), 256, 0, stream>>>(sel_key, sel_box, keep, pkc, out);
}

// Round 16
// 286.782 us; speedup vs baseline: 1.6338x; 1.0210x over previous
//
#include <hip/hip_runtime.h>
#include <cmath>

// Match XLA/numpy non-fused mul+add rounding everywhere (IoU / decode bit-faithfulness).
#pragma clang fp contract(off)

namespace {
constexpr int NIMG = 8;
constexpr int NLVL = 5;
constexpr int LH[5]   = {208,104,52,26,13};
constexpr int LW[5]   = {336,168,84,42,21};
constexpr int LSTR[5] = {4,8,16,32,64};
constexpr int HWA[5]  = {209664,52416,13104,3276,819};
constexpr int KSEL[5] = {2000,2000,2000,2000,819};
constexpr int SOFF[5] = {0,2000,4000,6000,8000};
constexpr int MTOT    = 8819;
constexpr int CAP     = 6144;          // per-(img,lvl) candidate cap (expect <= ~2600)
constexpr int NPAIR   = NIMG*NLVL;     // 40
constexpr int CCUM[5] = {52,65,69,70,71};  // cumulative ceil(HWA/4096) per level
constexpr int BLK_PER_IMG = 71;
constexpr int MASK_W  = 32;            // u64 words per NMS mask row (covers 2048 cols)
constexpr int OUTK    = 1000;

// workspace byte offsets (all 16B-aligned where needed)
constexpr size_t OFF_HIST   = 0;              // 40*4096*4      = 655360
constexpr size_t OFF_PKC    = 0;              // 40*2048*4 = 327680, aliases hist (dead after k_scan)
constexpr size_t OFF_CNT    = 655360;         // 40*4           = 160
constexpr size_t OFF_THR    = 655520;         // 40*4           = 160
constexpr size_t ZERO_BYTES = 655680;         // memset range (hist+cnt+thr)
constexpr size_t OFF_CAND   = 655872;         // 40*6144*4      = 983040  -> 1638912
constexpr size_t OFF_SELIDX = 1638912;        // 8*8819*4       = 282208  -> 1921120
constexpr size_t OFF_SELKEY = 1921120;        // 8*8819*8       = 564416  -> 2485536
constexpr size_t OFF_SELSC  = 2485536;        // 8*8819*4       = 282208  -> 2767744
constexpr size_t OFF_SELBOX = 2767744;        // 8*8819*16      = 1128832 -> 3896576
constexpr size_t OFF_MASK   = 3896576;        // 40*2000*32*8   = 20480000-> 24376576
constexpr size_t OFF_CKEY   = OFF_MASK;       // 40*6144*8 = 1.97MB aliases maskbuf (dead by k_masks)
constexpr size_t OFF_KEEP   = 24376576;       // 40*32*8        = 10240   -> 24386816
}

struct Ins {
  const float* cls[5];
  const float* reg[5];
  const int* ih;
  const int* iw;
};

__device__ __forceinline__ void decode_block(int b, int& img, int& lvl, int& chunk) {
  img = b / BLK_PER_IMG;
  int rb = b - img*BLK_PER_IMG;
  if      (rb < CCUM[0]) { lvl=0; chunk=rb; }
  else if (rb < CCUM[1]) { lvl=1; chunk=rb-CCUM[0]; }
  else if (rb < CCUM[2]) { lvl=2; chunk=rb-CCUM[1]; }
  else if (rb < CCUM[3]) { lvl=3; chunk=rb-CCUM[2]; }
  else                   { lvl=4; chunk=0; }
}

// order-preserving float->u32 map (total order over floats)
__device__ __forceinline__ unsigned mapbits(float x) {
  unsigned u = __float_as_uint(x);
  return u ^ (unsigned)(((int)u >> 31) | (int)0x80000000);
}

// fp32 sigmoid with correctly-rounded exp step: matches 1/(1+exp_f32(-x)) pipeline
__device__ __forceinline__ float sigmoid_ref(float x) {
  float e = (float)exp(-(double)x);   // correctly-rounded f32 exp(-x)
  return 1.0f / (1.0f + e);           // exact-IEEE add + div
}

// ---- K1: per-(img,lvl) 12-bit histogram of mapped logit bits ----
__global__ void k_hist(Ins in, unsigned* __restrict__ hist) {
  int img, lvl, chunk; decode_block(blockIdx.x, img, lvl, chunk);
  __shared__ unsigned lh[4096];
  for (int i = threadIdx.x; i < 4096; i += 256) lh[i] = 0;
  __syncthreads();
  const float* src = in.cls[lvl] + (size_t)img * HWA[lvl];
  int base = chunk * 4096;
  #pragma unroll
  for (int j = 0; j < 16; j++) {
    int e = base + j*256 + threadIdx.x;
    if (e < HWA[lvl]) {
      unsigned m = mapbits(src[e]);
      atomicAdd(&lh[m >> 20], 1u);
    }
  }
  __syncthreads();
  unsigned* gh = hist + (img*NLVL + lvl) * 4096;
  for (int i = threadIdx.x; i < 4096; i += 256)
    if (lh[i]) atomicAdd(&gh[i], lh[i]);
}

// ---- K2: find highest bin-edge with suffix count >= k ----
__global__ void k_scan(const unsigned* __restrict__ hist, unsigned* __restrict__ thr) {
  int pair = blockIdx.x; int lvl = pair % NLVL;
  const unsigned* h = hist + (size_t)pair * 4096;
  __shared__ unsigned part[256];
  unsigned s = 0;
  #pragma unroll
  for (int i = 0; i < 16; i++) s += h[threadIdx.x*16 + i];
  part[threadIdx.x] = s;
  __syncthreads();
  if (threadIdx.x == 0) {
    unsigned k = (unsigned)KSEL[lvl];
    unsigned cum = 0;
    unsigned edge = 0;
    for (int t = 255; t >= 0; t--) {
      if (cum + part[t] >= k) {
        for (int b = t*16 + 15; b >= t*16; b--) {
          cum += h[b];
          if (cum >= k) { edge = (unsigned)b; break; }
        }
        thr[pair] = edge << 20;
        return;
      }
      cum += part[t];
    }
    thr[pair] = 0u;
  }
}

// ---- K3: compact candidates; LDS block aggregation -> ONE global atomic/block ----
__global__ void __launch_bounds__(256) k_compact(Ins in, const unsigned* __restrict__ thr,
                          unsigned* __restrict__ cnt, unsigned* __restrict__ cand) {
  int img, lvl, chunk; decode_block(blockIdx.x, img, lvl, chunk);
  int pair = img*NLVL + lvl;
  unsigned T = thr[pair];
  const float* src = in.cls[lvl] + (size_t)img * HWA[lvl];
  int hw = LH[lvl] * LW[lvl];
  int base = chunk * 4096;
  int lid = threadIdx.x & 63;
  __shared__ unsigned lbuf[4096];      // block covers <=4096 elements: p always fits
  __shared__ unsigned lc, gbase;
  if (threadIdx.x == 0) lc = 0;
  __syncthreads();
  #pragma unroll
  for (int j = 0; j < 16; j++) {
    int e = base + j*256 + threadIdx.x;
    bool sel = (e < HWA[lvl]) && (mapbits(src[e]) >= T);
    unsigned long long mask = __ballot(sel);
    if (mask != 0ull) {
      int leader = __ffsll((long long)mask) - 1;
      unsigned wb = 0;
      if (lid == leader) wb = atomicAdd(&lc, (unsigned)__popcll(mask));  // LDS atomic
      wb = (unsigned)__shfl((int)wb, leader, 64);
      if (sel) {
        unsigned p = wb + (unsigned)__popcll(mask & ((1ull << lid) - 1ull));
        int a = e / hw;            // NCHW: e = a*hw + r
        int r = e - a*hw;
        lbuf[p] = (unsigned)(r*3 + a);  // score-space idx
      }
    }
  }
  __syncthreads();
  if (threadIdx.x == 0) gbase = atomicAdd(&cnt[pair], lc);  // one global atomic/block
  __syncthreads();
  unsigned nsel = lc, gb = gbase;
  for (unsigned t = threadIdx.x; t < nsel; t += 256) {
    unsigned p = gb + t;
    if (p < CAP) cand[(size_t)pair*CAP + p] = lbuf[t];      // coalesced
  }
}

// ---- K3b: compute sort keys ONCE per candidate (hoists dp-exp out of k_rank tiles) ----
__global__ void k_keys(Ins in, const unsigned* __restrict__ cntA,
                       const unsigned* __restrict__ cand,
                       unsigned long long* __restrict__ ckey) {
  int pair = blockIdx.y;
  int img = pair / NLVL, lvl = pair % NLVL;
  int c = min((int)cntA[pair], CAP);
  int j = blockIdx.x*256 + threadIdx.x;
  if (j >= c) return;
  unsigned idx = cand[(size_t)pair*CAP + j];
  int a = (int)(idx % 3u), r = (int)(idx / 3u);
  int hw = LH[lvl]*LW[lvl];
  float s = sigmoid_ref(in.cls[lvl][(size_t)img*HWA[lvl] + a*hw + r]);
  unsigned pack = ((unsigned)lvl << 18) | idx;   // < 2^21
  ckey[(size_t)pair*CAP + j] = ((unsigned long long)__float_as_uint(s) << 21)
                             | (unsigned long long)(0x1FFFFFu - pack);  // desc score, asc (lvl,idx)
}

// ---- K4: per-level exact rank (score desc, idx asc); scatter top-k into slots ----
__global__ void __launch_bounds__(256) k_rank(const unsigned* __restrict__ cntA,
                       const unsigned* __restrict__ cand,
                       const unsigned long long* __restrict__ ckey,
                       unsigned* __restrict__ sel_idx,
                       unsigned long long* __restrict__ sel_key,
                       float* __restrict__ sel_sc) {
  int pair = blockIdx.y; int tile = blockIdx.x;
  int img = pair / NLVL, lvl = pair % NLVL;
  int c = min((int)cntA[pair], CAP);
  if (tile*256 >= c) return;
  __shared__ unsigned long long keys[CAP];
  const unsigned long long* kp = ckey + (size_t)pair*CAP;
  for (int j = threadIdx.x; j < c; j += 256) keys[j] = kp[j];
  __syncthreads();
  int jj = tile*256 + threadIdx.x;
  if (jj >= c) return;
  unsigned long long mykey = keys[jj];
  int rk = 0;
  for (int j = 0; j < c; j++) rk += (keys[j] > mykey) ? 1 : 0;  // LDS broadcast
  if (rk < KSEL[lvl]) {
    int slot = img*MTOT + SOFF[lvl] + rk;
    sel_idx[slot] = cand[(size_t)pair*CAP + jj];
    sel_key[slot] = mykey;
    sel_sc[slot]  = __uint_as_float((unsigned)(mykey >> 21));
  }
}

// ---- K5: decode boxes (exact mmdet DeltaXYWH replication, clipped) ----
__global__ void k_decode(Ins in, const unsigned* __restrict__ sel_idx,
                         float* __restrict__ sel_box) {
  int t = blockIdx.x*256 + threadIdx.x;
  if (t >= NIMG*MTOT) return;
  int img = t / MTOT, pos = t - img*MTOT;
  int lvl = pos<2000?0 : pos<4000?1 : pos<6000?2 : pos<8000?3 : 4;
  unsigned idx = sel_idx[img*MTOT + pos];
  int a = (int)(idx % 3u);
  int r = (int)(idx / 3u);
  int Wl = LW[lvl]; int hw = LH[lvl]*Wl;
  int x = r % Wl, y = r / Wl;
  const float* rg = in.reg[lvl] + (size_t)img * 4 * HWA[lvl];  // 12*H*W
  float dx = rg[(a*4+0)*hw + r];
  float dy = rg[(a*4+1)*hw + r];
  float dw = rg[(a*4+2)*hw + r];
  float dh = rg[(a*4+3)*hw + r];
  float ratio = (a==0) ? 0.5f : (a==1) ? 1.0f : 2.0f;
  float hr = sqrtf(ratio);
  float wr = 1.0f / hr;
  float st = (float)LSTR[lvl];
  float wsz = st * wr * 8.0f;
  float hsz = st * hr * 8.0f;
  float xs = (float)x * st, ys = (float)y * st;
  float x1 = xs - wsz*0.5f, x2 = xs + wsz*0.5f;
  float y1 = ys - hsz*0.5f, y2 = ys + hsz*0.5f;
  float px = (x1 + x2) * 0.5f, py = (y1 + y2) * 0.5f;
  float pw = x2 - x1,          ph = y2 - y1;
  const float MR = 4.135166556742356f;
  dw = fminf(fmaxf(dw, -MR), MR);
  dh = fminf(fmaxf(dh, -MR), MR);
  float gx = px + pw*dx, gy = py + ph*dy;
  float gw = pw * (float)exp((double)dw);   // correctly-rounded f32 exp
  float gh = ph * (float)exp((double)dh);
  float Wi = (float)(*in.iw), Hi = (float)(*in.ih);
  float4 bb;
  bb.x = fminf(fmaxf(gx - gw*0.5f, 0.0f), Wi);
  bb.y = fminf(fmaxf(gy - gh*0.5f, 0.0f), Hi);
  bb.z = fminf(fmaxf(gx + gw*0.5f, 0.0f), Wi);
  bb.w = fminf(fmaxf(gy + gh*0.5f, 0.0f), Hi);
  ((float4*)sel_box)[img*MTOT + pos] = bb;
}

// ---- K6: NMS suppression-mask build — ballot tiles, 64 cols x 64 rows/wave ----
// Lane = column (bj + area in registers); rows broadcast from wave-private LDS.
// EXACT branch-free IoU>0.7: rn_f32(inter/u) > 0.7f  <=>  inter/u >= Md where
// Md = midpoint(0.7f, succ(0.7f)) (tie-to-even lands on succ > 0.7f). With
// u > 0: sup = (double)inter >= Md*(double)u — Md has 25 mantissa bits, u has
// 24, product exact in f64; comparisons exact => bit-identical to reference's
// rounded division. No margin, no divergent div path, no second ballot.
// OOB columns get a degenerate far box (inter=0 -> sup=false): no colmask.
// Diagonal tiles take a separate loop (u64 masking hoisted off the hot path).
__global__ void __launch_bounds__(256) k_masks(const float* __restrict__ sel_box,
                        unsigned long long* __restrict__ maskbuf) {
  int pair = blockIdx.y; int lvl = pair % NLVL; int img = pair / NLVL;
  int n = KSEL[lvl];
  int nw = (n + 63) >> 6;
  int wv = threadIdx.x >> 6;
  int lane = threadIdx.x & 63;
  int t = blockIdx.x * 4 + wv;           // flat triangular tile id
  int ntile = nw * (nw + 1) / 2;
  if (t >= ntile) return;                // wave-level exit (no barriers used)
  int rb = 0, cum = 0;
  while (cum + (nw - rb) <= t) { cum += nw - rb; rb++; }
  int jw = rb + (t - cum);               // word strip; jw >= rb (upper-tri)
  const float4* boxes = ((const float4*)sel_box) + img*MTOT + SOFF[lvl];
  float off = (float)lvl * 4096.0f;
  // columns: this lane's box in registers; OOB -> degenerate (never suppresses)
  int col = jw*64 + lane;
  float bjx, bjy, bjz, bjw2, aj;
  if (col < n) {
    float4 bj = boxes[col];
    bjx = bj.x + off; bjy = bj.y + off; bjz = bj.z + off; bjw2 = bj.w + off;
    aj = (bjz - bjx) * (bjw2 - bjy);
  } else {
    bjx = 3.0e8f; bjy = 3.0e8f; bjz = 3.0e8f; bjw2 = 3.0e8f;   // inter=0, aj=0
    aj = 0.0f;
  }
  // rows: stage this wave's 64 row boxes + areas (wave-private LDS segment)
  __shared__ float4 srow[4][64];
  __shared__ float  sarea[4][64];
  int row0 = rb*64;
  {
    float4 bi0 = boxes[min(row0 + lane, n-1)];
    bi0.x += off; bi0.y += off; bi0.z += off; bi0.w += off;
    srow[wv][lane] = bi0;
    sarea[wv][lane] = (bi0.z - bi0.x) * (bi0.w - bi0.y);
  }
  // (wave-synchronous LDS: compiler inserts lgkmcnt wait before reads)
  const double Md = 0.70000001788139343261718750;  // (0.7f + succ(0.7f))/2 exact
  unsigned long long acc = 0ull;
  if (jw > rb) {
    #pragma unroll 4
    for (int r = 0; r < 64; r++) {
      float4 bi = srow[wv][r];           // LDS broadcast (uniform address)
      float ai = sarea[wv][r];
      float xx1 = fmaxf(bi.x, bjx), yy1 = fmaxf(bi.y, bjy);
      float xx2 = fminf(bi.z, bjz), yy2 = fminf(bi.w, bjw2);
      float iw_ = fmaxf(xx2 - xx1, 0.0f), ih_ = fmaxf(yy2 - yy1, 0.0f);
      float inter = iw_ * ih_;
      float u = fmaxf((ai + aj) - inter, 1e-6f);
      bool sup = (double)inter >= Md * (double)u;  // exact rn(inter/u) > 0.7f
      unsigned long long word = __ballot(sup);
      if (lane == r) acc = word;
    }
  } else {
    #pragma unroll 4
    for (int r = 0; r < 64; r++) {
      float4 bi = srow[wv][r];
      float ai = sarea[wv][r];
      float xx1 = fmaxf(bi.x, bjx), yy1 = fmaxf(bi.y, bjy);
      float xx2 = fminf(bi.z, bjz), yy2 = fminf(bi.w, bjw2);
      float iw_ = fmaxf(xx2 - xx1, 0.0f), ih_ = fmaxf(yy2 - yy1, 0.0f);
      float inter = iw_ * ih_;
      float u = fmaxf((ai + aj) - inter, 1e-6f);
      bool sup = (double)inter >= Md * (double)u;
      unsigned long long word = __ballot(sup) & ~((2ull << r) - 1ull);  // j > i
      if (lane == r) acc = word;
    }
  }
  // one store per tile row; guarded to rows < n (no cross-pair spill)
  if (row0 + lane < n)
    maskbuf[(size_t)pair*2000*MASK_W + (size_t)(row0 + lane)*MASK_W + jw] = acc;
}

// ---- K7: EXACT one-pass block-sequential greedy NMS (1024 threads per pair) ----
// Per 64-box block k: (1) all threads hold word w of 2 block rows in a register
// DOUBLE BUFFER (loads for k+1 issued a full block early; only 4 u64 live ->
// no spill/sink pressure); (2) wave 0 runs the in-block triangle as a register
// Jacobi with wave-OR butterflies (no memory, no readlane-on-pending-load);
// (3) alive rows' words atomicOr into 32-word LDS rem. 3 barriers/block.
__global__ void __launch_bounds__(1024) k_nms(const unsigned long long* __restrict__ maskbuf,
                      unsigned long long* __restrict__ keep) {
  int pair = blockIdx.x; int lvl = pair % NLVL;
  int n = KSEL[lvl];
  int nw = (n + 63) >> 6;
  const unsigned long long* mrow = maskbuf + (size_t)pair*2000*MASK_W;
  int tid = threadIdx.x;
  int w  = tid & 31;                 // word owned (0..31)
  int rg = tid >> 5;                 // row group (0..31): rows rg*2, rg*2+1
  __shared__ unsigned long long rem[32];   // suppression from finalized kept boxes
  __shared__ unsigned long long diag[64];  // word k of current block's rows
  __shared__ unsigned long long sSk;       // final suppressed mask of block k
  if (tid < 32) rem[tid] = 0ull;
  __syncthreads();

  unsigned long long A0, A1, B0, B1;
  {
    int r0 = min(rg*2, n-1), r1 = min(rg*2+1, n-1);
    A0 = mrow[(size_t)r0*MASK_W + w];
    A1 = mrow[(size_t)r1*MASK_W + w];
  }
  for (int k = 0; k < nw; k++) {
    if (k + 1 < nw) {                // prefetch block k+1 (consumed next iter)
      int r0 = min(64*(k+1) + rg*2, n-1), r1 = min(64*(k+1) + rg*2 + 1, n-1);
      B0 = mrow[(size_t)r0*MASK_W + w];
      B1 = mrow[(size_t)r1*MASK_W + w];
    }
    if (w == k) { diag[rg*2] = A0; diag[rg*2+1] = A1; }
    __syncthreads();
    if (tid < 64) {                  // wave 0: in-block register Jacobi
      int row = 64*k + tid;
      bool valid = row < n;
      unsigned long long D = valid ? diag[tid] : 0ull;   // already strictly upper
      unsigned long long rk = rem[k];
      unsigned long long S = rk;
      for (int it = 0; it < 64; it++) {
        bool kept = valid && !((S >> tid) & 1ull);
        unsigned long long c = kept ? D : 0ull;
        #pragma unroll
        for (int m = 1; m < 64; m <<= 1) {               // wave-wide OR
          unsigned lo = (unsigned)__shfl_xor((int)(unsigned)(c & 0xffffffffull), m, 64);
          unsigned hi = (unsigned)__shfl_xor((int)(unsigned)(c >> 32), m, 64);
          c |= ((unsigned long long)hi << 32) | (unsigned long long)lo;
        }
        unsigned long long Snew = rk | c;                // uniform across wave
        if (Snew == S) break;                            // fixpoint (<= depth iters)
        S = Snew;
      }
      if (tid == 0) {
        sSk = S;
        int nb = n - 64*k;
        unsigned long long vm = (nb >= 64) ? ~0ull : ((1ull << nb) - 1ull);
        keep[(size_t)pair*MASK_W + k] = (~S) & vm;
      }
    }
    __syncthreads();
    if (w > k) {                     // accumulate alive rows into later words
      unsigned long long Sk = sSk;
      int r0 = 64*k + rg*2, r1 = r0 + 1;
      unsigned long long m = 0ull;
      if (r0 < n && !((Sk >> (rg*2)) & 1ull))     m |= A0;
      if (r1 < n && !((Sk >> (rg*2+1)) & 1ull))   m |= A1;
      if (m) atomicOr(&rem[w], m);
    }
    __syncthreads();
    A0 = B0; A1 = B1;
  }
}

// ---- K7b: inclusive prefix-count of kept per (img,lvl) position ----
__global__ void __launch_bounds__(64) k_pfx(const unsigned long long* __restrict__ keep,
                                            int* __restrict__ pkc) {
  int pair = blockIdx.x; int lvl = pair % NLVL;
  int n = KSEL[lvl];
  int nw = (n + 63) >> 6;
  int lane = threadIdx.x;
  unsigned long long w = (lane < nw) ? keep[(size_t)pair*MASK_W + lane] : 0ull;
  if (lane == nw - 1 && (n & 63)) w &= (1ull << (n & 63)) - 1ull;  // bits >= n are garbage
  __shared__ int lcnt[64];
  lcnt[lane] = __popcll(w);
  __syncthreads();
  int pre = 0;
  for (int t = 0; t < lane; t++) pre += lcnt[t];   // <=63 LDS adds, one wave — fine
  for (int b = 0; b < 64; b++) {
    int p = lane*64 + b;
    if (p < n) {
      pre += (int)((w >> b) & 1ull);
      pkc[pair*2048 + p] = pre;
    }
  }
}

// ---- K8: rank kept boxes via per-level prefix counts + 4 binary searches ----
__global__ void __launch_bounds__(256) k_out2(const unsigned long long* __restrict__ sel_key,
                      const float* __restrict__ sel_box,
                      const unsigned long long* __restrict__ keep,
                      const int* __restrict__ pkc,
                      float* __restrict__ out) {
  int img = blockIdx.y;
  int pos = blockIdx.x*256 + threadIdx.x;
  if (pos >= MTOT) return;
  int lvl = pos<2000?0 : pos<4000?1 : pos<6000?2 : pos<8000?3 : 4;
  int local = pos - SOFF[lvl];
  int pair = img*NLVL + lvl;
  unsigned long long kw = keep[(size_t)pair*MASK_W + (local >> 6)];
  if (!((kw >> (local & 63)) & 1ull)) return;
  unsigned long long mykey = sel_key[img*MTOT + pos];
  int rank = pkc[pair*2048 + local] - 1;    // kept before me within my level
  #pragma unroll
  for (int l2 = 0; l2 < NLVL; l2++) {
    if (l2 == lvl) continue;
    const unsigned long long* A = sel_key + img*MTOT + SOFF[l2];
    int lo = 0, hi = KSEL[l2];
    while (lo < hi) {
      int mid = (lo + hi) >> 1;
      if (A[mid] > mykey) lo = mid + 1; else hi = mid;
    }
    if (lo > 0) rank += pkc[(img*NLVL + l2)*2048 + lo - 1];
  }
  if (rank < OUTK) {
    ((float4*)out)[img*OUTK + rank] = ((const float4*)sel_box)[img*MTOT + pos];
    out[NIMG*OUTK*4 + img*OUTK + rank] = __uint_as_float((unsigned)(mykey >> 21));
  }
}

extern "C" void kernel_launch(void* const* d_in, const int* in_sizes, int n_in,
                              void* d_out, int out_size, void* d_ws, size_t ws_size,
                              hipStream_t stream) {
  Ins in;
  // setup_inputs dict order: cls_0, reg_0, cls_1, reg_1, ..., cls_4, reg_4, image_h, image_w
  for (int l = 0; l < 5; l++) {
    in.cls[l] = (const float*)d_in[2*l];
    in.reg[l] = (const float*)d_in[2*l + 1];
  }
  in.ih = (const int*)d_in[10];
  in.iw = (const int*)d_in[11];

  char* ws = (char*)d_ws;
  unsigned* hist              = (unsigned*)(ws + OFF_HIST);
  int* pkc                    = (int*)(ws + OFF_PKC);          // aliases hist (dead after k_scan)
  unsigned* cnt               = (unsigned*)(ws + OFF_CNT);
  unsigned* thr               = (unsigned*)(ws + OFF_THR);
  unsigned* cand              = (unsigned*)(ws + OFF_CAND);
  unsigned* sel_idx           = (unsigned*)(ws + OFF_SELIDX);
  unsigned long long* sel_key = (unsigned long long*)(ws + OFF_SELKEY);
  float* sel_sc               = (float*)(ws + OFF_SELSC);
  float* sel_box              = (float*)(ws + OFF_SELBOX);
  unsigned long long* maskbuf = (unsigned long long*)(ws + OFF_MASK);
  unsigned long long* ckey    = (unsigned long long*)(ws + OFF_CKEY);  // aliases maskbuf (dead before k_masks)
  unsigned long long* keep    = (unsigned long long*)(ws + OFF_KEEP);
  float* out                  = (float*)d_out;

  hipMemsetAsync(d_ws, 0, ZERO_BYTES, stream);                 // hist + counters + thr
  hipMemsetAsync(d_out, 0, (size_t)NIMG*OUTK*5*sizeof(float), stream); // zero-padded outputs

  k_hist   <<<NIMG*BLK_PER_IMG, 256, 0, stream>>>(in, hist);
  k_scan   <<<NPAIR, 256, 0, stream>>>(hist, thr);
  k_compact<<<NIMG*BLK_PER_IMG, 256, 0, stream>>>(in, thr, cnt, cand);
  k_keys   <<<dim3(CAP/256, NPAIR), 256, 0, stream>>>(in, cnt, cand, ckey);
  k_rank   <<<dim3(CAP/256, NPAIR), 256, 0, stream>>>(cnt, cand, ckey, sel_idx, sel_key, sel_sc);
  k_decode <<<(NIMG*MTOT + 255)/256, 256, 0, stream>>>(in, sel_idx, sel_box);
  k_masks  <<<dim3(132, NPAIR), 256, 0, stream>>>(sel_box, maskbuf);
  k_nms    <<<NPAIR, 1024, 0, stream>>>(maskbuf, keep);
  k_pfx    <<<NPAIR, 64, 0, stream>>>(keep, pkc);
  k_out2   <<<dim3((MTOT + 255)/256, NIMG), 256, 0, stream>>>(sel_key, sel_box, keep, pkc, out);
}

// Round 18
// 283.488 us; speedup vs baseline: 1.6528x; 1.0116x over previous
//
#include <hip/hip_runtime.h>
#include <cmath>

// Match XLA/numpy non-fused mul+add rounding everywhere (IoU / decode bit-faithfulness).
#pragma clang fp contract(off)

namespace {
constexpr int NIMG = 8;
constexpr int NLVL = 5;
constexpr int LH[5]   = {208,104,52,26,13};
constexpr int LW[5]   = {336,168,84,42,21};
constexpr int LSTR[5] = {4,8,16,32,64};
constexpr int HWA[5]  = {209664,52416,13104,3276,819};
constexpr int KSEL[5] = {2000,2000,2000,2000,819};
constexpr int SOFF[5] = {0,2000,4000,6000,8000};
constexpr int MTOT    = 8819;
constexpr int CAP     = 6144;          // per-(img,lvl) candidate cap (expect <= ~2600)
constexpr int NPAIR   = NIMG*NLVL;     // 40
constexpr int CCUM[5] = {52,65,69,70,71};  // cumulative ceil(HWA/4096) per level
constexpr int BLK_PER_IMG = 71;
constexpr int MASK_W  = 32;            // u64 words per NMS mask row (covers 2048 cols)
constexpr int OUTK    = 1000;

// workspace byte offsets (all 16B-aligned where needed)
constexpr size_t OFF_HIST   = 0;              // 40*4096*4      = 655360
constexpr size_t OFF_PKC    = 0;              // 40*2048*4 = 327680, aliases hist (dead after k_scan)
constexpr size_t OFF_CNT    = 655360;         // 40*4           = 160
constexpr size_t OFF_THR    = 655520;         // 40*4           = 160
constexpr size_t ZERO_BYTES = 655680;         // memset range (hist+cnt+thr)
constexpr size_t OFF_CAND   = 655872;         // 40*6144*4      = 983040  -> 1638912
constexpr size_t OFF_SELIDX = 1638912;        // 8*8819*4       = 282208  -> 1921120
constexpr size_t OFF_SELKEY = 1921120;        // 8*8819*8       = 564416  -> 2485536
constexpr size_t OFF_SELSC  = 2485536;        // 8*8819*4       = 282208  -> 2767744
constexpr size_t OFF_SELBOX = 2767744;        // 8*8819*16      = 1128832 -> 3896576
constexpr size_t OFF_MASK   = 3896576;        // 40*2000*32*8   = 20480000-> 24376576
constexpr size_t OFF_CKEY   = OFF_MASK;       // 40*6144*8 = 1.97MB aliases maskbuf (dead by k_masks)
constexpr size_t OFF_KEEP   = 24376576;       // 40*32*8        = 10240   -> 24386816
}

struct Ins {
  const float* cls[5];
  const float* reg[5];
  const int* ih;
  const int* iw;
};

__device__ __forceinline__ void decode_block(int b, int& img, int& lvl, int& chunk) {
  img = b / BLK_PER_IMG;
  int rb = b - img*BLK_PER_IMG;
  if      (rb < CCUM[0]) { lvl=0; chunk=rb; }
  else if (rb < CCUM[1]) { lvl=1; chunk=rb-CCUM[0]; }
  else if (rb < CCUM[2]) { lvl=2; chunk=rb-CCUM[1]; }
  else if (rb < CCUM[3]) { lvl=3; chunk=rb-CCUM[2]; }
  else                   { lvl=4; chunk=0; }
}

// order-preserving float->u32 map (total order over floats)
__device__ __forceinline__ unsigned mapbits(float x) {
  unsigned u = __float_as_uint(x);
  return u ^ (unsigned)(((int)u >> 31) | (int)0x80000000);
}

// fp32 sigmoid with correctly-rounded exp step: matches 1/(1+exp_f32(-x)) pipeline
__device__ __forceinline__ float sigmoid_ref(float x) {
  float e = (float)exp(-(double)x);   // correctly-rounded f32 exp(-x)
  return 1.0f / (1.0f + e);           // exact-IEEE add + div
}

// ---- K1: per-(img,lvl) 12-bit histogram of mapped logit bits ----
__global__ void k_hist(Ins in, unsigned* __restrict__ hist) {
  int img, lvl, chunk; decode_block(blockIdx.x, img, lvl, chunk);
  __shared__ unsigned lh[4096];
  for (int i = threadIdx.x; i < 4096; i += 256) lh[i] = 0;
  __syncthreads();
  const float* src = in.cls[lvl] + (size_t)img * HWA[lvl];
  int base = chunk * 4096;
  #pragma unroll
  for (int j = 0; j < 16; j++) {
    int e = base + j*256 + threadIdx.x;
    if (e < HWA[lvl]) {
      unsigned m = mapbits(src[e]);
      atomicAdd(&lh[m >> 20], 1u);
    }
  }
  __syncthreads();
  unsigned* gh = hist + (img*NLVL + lvl) * 4096;
  for (int i = threadIdx.x; i < 4096; i += 256)
    if (lh[i]) atomicAdd(&gh[i], lh[i]);
}

// ---- K2: find highest bin-edge with suffix count >= k ----
__global__ void k_scan(const unsigned* __restrict__ hist, unsigned* __restrict__ thr) {
  int pair = blockIdx.x; int lvl = pair % NLVL;
  const unsigned* h = hist + (size_t)pair * 4096;
  __shared__ unsigned part[256];
  unsigned s = 0;
  #pragma unroll
  for (int i = 0; i < 16; i++) s += h[threadIdx.x*16 + i];
  part[threadIdx.x] = s;
  __syncthreads();
  if (threadIdx.x == 0) {
    unsigned k = (unsigned)KSEL[lvl];
    unsigned cum = 0;
    unsigned edge = 0;
    for (int t = 255; t >= 0; t--) {
      if (cum + part[t] >= k) {
        for (int b = t*16 + 15; b >= t*16; b--) {
          cum += h[b];
          if (cum >= k) { edge = (unsigned)b; break; }
        }
        thr[pair] = edge << 20;
        return;
      }
      cum += part[t];
    }
    thr[pair] = 0u;
  }
}

// ---- K3: compact candidates + compute sort keys in the same pass ----
// (k_keys fused in: logit value is already in a register at selection time;
//  dp-exp runs only on selected lanes. LDS-batched -> one global atomic/block.)
__global__ void __launch_bounds__(256) k_compact(Ins in, const unsigned* __restrict__ thr,
                          unsigned* __restrict__ cnt, unsigned* __restrict__ cand,
                          unsigned long long* __restrict__ ckey) {
  int img, lvl, chunk; decode_block(blockIdx.x, img, lvl, chunk);
  int pair = img*NLVL + lvl;
  unsigned T = thr[pair];
  const float* src = in.cls[lvl] + (size_t)img * HWA[lvl];
  int hw = LH[lvl] * LW[lvl];
  int base = chunk * 4096;
  int lid = threadIdx.x & 63;
  __shared__ unsigned lbuf[4096];            // block covers <=4096 elements
  __shared__ unsigned long long lkey[4096];  // 32KB key staging
  __shared__ unsigned lc, gbase;
  if (threadIdx.x == 0) lc = 0;
  __syncthreads();
  #pragma unroll
  for (int j = 0; j < 16; j++) {
    int e = base + j*256 + threadIdx.x;
    float v = 0.0f;
    bool inb = (e < HWA[lvl]);
    if (inb) v = src[e];
    bool sel = inb && (mapbits(v) >= T);
    unsigned long long mask = __ballot(sel);
    if (mask != 0ull) {
      int leader = __ffsll((long long)mask) - 1;
      unsigned wb = 0;
      if (lid == leader) wb = atomicAdd(&lc, (unsigned)__popcll(mask));  // LDS atomic
      wb = (unsigned)__shfl((int)wb, leader, 64);
      if (sel) {
        unsigned p = wb + (unsigned)__popcll(mask & ((1ull << lid) - 1ull));
        int a = e / hw;            // NCHW: e = a*hw + r
        int r = e - a*hw;
        unsigned idx = (unsigned)(r*3 + a);  // score-space idx
        lbuf[p] = idx;
        float s = sigmoid_ref(v);            // dp-exp on selected lanes only
        unsigned pack = ((unsigned)lvl << 18) | idx;   // < 2^21
        lkey[p] = ((unsigned long long)__float_as_uint(s) << 21)
                | (unsigned long long)(0x1FFFFFu - pack);  // desc score, asc (lvl,idx)
      }
    }
  }
  __syncthreads();
  if (threadIdx.x == 0) gbase = atomicAdd(&cnt[pair], lc);  // one global atomic/block
  __syncthreads();
  unsigned nsel = lc, gb = gbase;
  for (unsigned t = threadIdx.x; t < nsel; t += 256) {
    unsigned p = gb + t;
    if (p < CAP) {
      cand[(size_t)pair*CAP + p] = lbuf[t];                 // coalesced
      ckey[(size_t)pair*CAP + p] = lkey[t];
    }
  }
}

// ---- K4: per-level exact rank (score desc, idx asc); scatter top-k into slots ----
__global__ void __launch_bounds__(256) k_rank(const unsigned* __restrict__ cntA,
                       const unsigned* __restrict__ cand,
                       const unsigned long long* __restrict__ ckey,
                       unsigned* __restrict__ sel_idx,
                       unsigned long long* __restrict__ sel_key,
                       float* __restrict__ sel_sc) {
  int pair = blockIdx.y; int tile = blockIdx.x;
  int img = pair / NLVL, lvl = pair % NLVL;
  int c = min((int)cntA[pair], CAP);
  if (tile*256 >= c) return;
  __shared__ unsigned long long keys[CAP];
  const unsigned long long* kp = ckey + (size_t)pair*CAP;
  for (int j = threadIdx.x; j < c; j += 256) keys[j] = kp[j];
  __syncthreads();
  int jj = tile*256 + threadIdx.x;
  if (jj >= c) return;
  unsigned long long mykey = keys[jj];
  int rk = 0;
  for (int j = 0; j < c; j++) rk += (keys[j] > mykey) ? 1 : 0;  // LDS broadcast
  if (rk < KSEL[lvl]) {
    int slot = img*MTOT + SOFF[lvl] + rk;
    sel_idx[slot] = cand[(size_t)pair*CAP + jj];
    sel_key[slot] = mykey;
    sel_sc[slot]  = __uint_as_float((unsigned)(mykey >> 21));
  }
}

// ---- K5: decode boxes (exact mmdet DeltaXYWH replication, clipped) ----
__global__ void k_decode(Ins in, const unsigned* __restrict__ sel_idx,
                         float* __restrict__ sel_box) {
  int t = blockIdx.x*256 + threadIdx.x;
  if (t >= NIMG*MTOT) return;
  int img = t / MTOT, pos = t - img*MTOT;
  int lvl = pos<2000?0 : pos<4000?1 : pos<6000?2 : pos<8000?3 : 4;
  unsigned idx = sel_idx[img*MTOT + pos];
  int a = (int)(idx % 3u);
  int r = (int)(idx / 3u);
  int Wl = LW[lvl]; int hw = LH[lvl]*Wl;
  int x = r % Wl, y = r / Wl;
  const float* rg = in.reg[lvl] + (size_t)img * 4 * HWA[lvl];  // 12*H*W
  float dx = rg[(a*4+0)*hw + r];
  float dy = rg[(a*4+1)*hw + r];
  float dw = rg[(a*4+2)*hw + r];
  float dh = rg[(a*4+3)*hw + r];
  float ratio = (a==0) ? 0.5f : (a==1) ? 1.0f : 2.0f;
  float hr = sqrtf(ratio);
  float wr = 1.0f / hr;
  float st = (float)LSTR[lvl];
  float wsz = st * wr * 8.0f;
  float hsz = st * hr * 8.0f;
  float xs = (float)x * st, ys = (float)y * st;
  float x1 = xs - wsz*0.5f, x2 = xs + wsz*0.5f;
  float y1 = ys - hsz*0.5f, y2 = ys + hsz*0.5f;
  float px = (x1 + x2) * 0.5f, py = (y1 + y2) * 0.5f;
  float pw = x2 - x1,          ph = y2 - y1;
  const float MR = 4.135166556742356f;
  dw = fminf(fmaxf(dw, -MR), MR);
  dh = fminf(fmaxf(dh, -MR), MR);
  float gx = px + pw*dx, gy = py + ph*dy;
  float gw = pw * (float)exp((double)dw);   // correctly-rounded f32 exp
  float gh = ph * (float)exp((double)dh);
  float Wi = (float)(*in.iw), Hi = (float)(*in.ih);
  float4 bb;
  bb.x = fminf(fmaxf(gx - gw*0.5f, 0.0f), Wi);
  bb.y = fminf(fmaxf(gy - gh*0.5f, 0.0f), Hi);
  bb.z = fminf(fmaxf(gx + gw*0.5f, 0.0f), Wi);
  bb.w = fminf(fmaxf(gy + gh*0.5f, 0.0f), Hi);
  ((float4*)sel_box)[img*MTOT + pos] = bb;
}

// ---- K6: NMS suppression-mask build — ballot tiles, 64 cols x 64 rows/wave ----
// Lane = column (bj + area in registers); rows broadcast from wave-private LDS.
// Area recomputed from bi (no second LDS array), unroll 16 (immediate LDS
// offsets). EXACT branch-free IoU>0.7 via f64: sup = (double)inter >=
// Md*(double)u, Md = midpoint(0.7f, succ(0.7f)) — exact product (25+24 bits
// <= 53) => bit-identical to the reference's rounded f32 division.
// OOB columns get a degenerate far box (inter=0 -> never suppress).
__global__ void __launch_bounds__(256) k_masks(const float* __restrict__ sel_box,
                        unsigned long long* __restrict__ maskbuf) {
  int pair = blockIdx.y; int lvl = pair % NLVL; int img = pair / NLVL;
  int n = KSEL[lvl];
  int nw = (n + 63) >> 6;
  int wv = threadIdx.x >> 6;
  int lane = threadIdx.x & 63;
  int t = blockIdx.x * 4 + wv;           // flat triangular tile id
  int ntile = nw * (nw + 1) / 2;
  if (t >= ntile) return;                // wave-level exit (no barriers used)
  int rb = 0, cum = 0;
  while (cum + (nw - rb) <= t) { cum += nw - rb; rb++; }
  int jw = rb + (t - cum);               // word strip; jw >= rb (upper-tri)
  const float4* boxes = ((const float4*)sel_box) + img*MTOT + SOFF[lvl];
  float off = (float)lvl * 4096.0f;
  // columns: this lane's box in registers; OOB -> degenerate (never suppresses)
  int col = jw*64 + lane;
  float bjx, bjy, bjz, bjw2, aj;
  if (col < n) {
    float4 bj = boxes[col];
    bjx = bj.x + off; bjy = bj.y + off; bjz = bj.z + off; bjw2 = bj.w + off;
    aj = (bjz - bjx) * (bjw2 - bjy);
  } else {
    bjx = 3.0e8f; bjy = 3.0e8f; bjz = 3.0e8f; bjw2 = 3.0e8f;   // inter=0, aj=0
    aj = 0.0f;
  }
  // rows: stage this wave's 64 row boxes (wave-private LDS segment)
  __shared__ float4 srow[4][64];
  int row0 = rb*64;
  {
    float4 bi0 = boxes[min(row0 + lane, n-1)];
    bi0.x += off; bi0.y += off; bi0.z += off; bi0.w += off;
    srow[wv][lane] = bi0;
  }
  // (wave-synchronous LDS: compiler inserts lgkmcnt wait before reads)
  const double Md = 0.70000001788139343261718750;  // (0.7f + succ(0.7f))/2 exact
  unsigned long long acc = 0ull;
  if (jw > rb) {
    #pragma unroll 16
    for (int r = 0; r < 64; r++) {
      float4 bi = srow[wv][r];           // LDS broadcast (uniform address)
      float ai = (bi.z - bi.x) * (bi.w - bi.y);
      float xx1 = fmaxf(bi.x, bjx), yy1 = fmaxf(bi.y, bjy);
      float xx2 = fminf(bi.z, bjz), yy2 = fminf(bi.w, bjw2);
      float iw_ = fmaxf(xx2 - xx1, 0.0f), ih_ = fmaxf(yy2 - yy1, 0.0f);
      float inter = iw_ * ih_;
      float u = fmaxf((ai + aj) - inter, 1e-6f);
      bool sup = (double)inter >= Md * (double)u;  // exact rn(inter/u) > 0.7f
      unsigned long long word = __ballot(sup);
      if (lane == r) acc = word;
    }
  } else {
    #pragma unroll 16
    for (int r = 0; r < 64; r++) {
      float4 bi = srow[wv][r];
      float ai = (bi.z - bi.x) * (bi.w - bi.y);
      float xx1 = fmaxf(bi.x, bjx), yy1 = fmaxf(bi.y, bjy);
      float xx2 = fminf(bi.z, bjz), yy2 = fminf(bi.w, bjw2);
      float iw_ = fmaxf(xx2 - xx1, 0.0f), ih_ = fmaxf(yy2 - yy1, 0.0f);
      float inter = iw_ * ih_;
      float u = fmaxf((ai + aj) - inter, 1e-6f);
      bool sup = (double)inter >= Md * (double)u;
      unsigned long long word = __ballot(sup) & ~((2ull << r) - 1ull);  // j > i (SALU)
      if (lane == r) acc = word;
    }
  }
  // one store per tile row; guarded to rows < n (no cross-pair spill)
  if (row0 + lane < n)
    maskbuf[(size_t)pair*2000*MASK_W + (size_t)(row0 + lane)*MASK_W + jw] = acc;
}

// ---- K7: EXACT one-pass block-sequential greedy NMS (1024 threads per pair) ----
// Per 64-box block k: (1) all threads hold word w of 2 block rows in a register
// DOUBLE BUFFER (loads for k+1 issued a full block early; only 4 u64 live ->
// no spill/sink pressure); (2) wave 0 runs the in-block triangle as a register
// Jacobi with wave-OR butterflies (no memory, no readlane-on-pending-load);
// (3) alive rows' words atomicOr into 32-word LDS rem. 3 barriers/block.
__global__ void __launch_bounds__(1024) k_nms(const unsigned long long* __restrict__ maskbuf,
                      unsigned long long* __restrict__ keep) {
  int pair = blockIdx.x; int lvl = pair % NLVL;
  int n = KSEL[lvl];
  int nw = (n + 63) >> 6;
  const unsigned long long* mrow = maskbuf + (size_t)pair*2000*MASK_W;
  int tid = threadIdx.x;
  int w  = tid & 31;                 // word owned (0..31)
  int rg = tid >> 5;                 // row group (0..31): rows rg*2, rg*2+1
  __shared__ unsigned long long rem[32];   // suppression from finalized kept boxes
  __shared__ unsigned long long diag[64];  // word k of current block's rows
  __shared__ unsigned long long sSk;       // final suppressed mask of block k
  if (tid < 32) rem[tid] = 0ull;
  __syncthreads();

  unsigned long long A0, A1, B0, B1;
  {
    int r0 = min(rg*2, n-1), r1 = min(rg*2+1, n-1);
    A0 = mrow[(size_t)r0*MASK_W + w];
    A1 = mrow[(size_t)r1*MASK_W + w];
  }
  for (int k = 0; k < nw; k++) {
    if (k + 1 < nw) {                // prefetch block k+1 (consumed next iter)
      int r0 = min(64*(k+1) + rg*2, n-1), r1 = min(64*(k+1) + rg*2 + 1, n-1);
      B0 = mrow[(size_t)r0*MASK_W + w];
      B1 = mrow[(size_t)r1*MASK_W + w];
    }
    if (w == k) { diag[rg*2] = A0; diag[rg*2+1] = A1; }
    __syncthreads();
    if (tid < 64) {                  // wave 0: in-block register Jacobi
      int row = 64*k + tid;
      bool valid = row < n;
      unsigned long long D = valid ? diag[tid] : 0ull;   // already strictly upper
      unsigned long long rk = rem[k];
      unsigned long long S = rk;
      for (int it = 0; it < 64; it++) {
        bool kept = valid && !((S >> tid) & 1ull);
        unsigned long long c = kept ? D : 0ull;
        #pragma unroll
        for (int m = 1; m < 64; m <<= 1) {               // wave-wide OR
          unsigned lo = (unsigned)__shfl_xor((int)(unsigned)(c & 0xffffffffull), m, 64);
          unsigned hi = (unsigned)__shfl_xor((int)(unsigned)(c >> 32), m, 64);
          c |= ((unsigned long long)hi << 32) | (unsigned long long)lo;
        }
        unsigned long long Snew = rk | c;                // uniform across wave
        if (Snew == S) break;                            // fixpoint (<= depth iters)
        S = Snew;
      }
      if (tid == 0) {
        sSk = S;
        int nb = n - 64*k;
        unsigned long long vm = (nb >= 64) ? ~0ull : ((1ull << nb) - 1ull);
        keep[(size_t)pair*MASK_W + k] = (~S) & vm;
      }
    }
    __syncthreads();
    if (w > k) {                     // accumulate alive rows into later words
      unsigned long long Sk = sSk;
      int r0 = 64*k + rg*2, r1 = r0 + 1;
      unsigned long long m = 0ull;
      if (r0 < n && !((Sk >> (rg*2)) & 1ull))     m |= A0;
      if (r1 < n && !((Sk >> (rg*2+1)) & 1ull))   m |= A1;
      if (m) atomicOr(&rem[w], m);
    }
    __syncthreads();
    A0 = B0; A1 = B1;
  }
}

// ---- K7b: inclusive prefix-count of kept per (img,lvl) position ----
__global__ void __launch_bounds__(64) k_pfx(const unsigned long long* __restrict__ keep,
                                            int* __restrict__ pkc) {
  int pair = blockIdx.x; int lvl = pair % NLVL;
  int n = KSEL[lvl];
  int nw = (n + 63) >> 6;
  int lane = threadIdx.x;
  unsigned long long w = (lane < nw) ? keep[(size_t)pair*MASK_W + lane] : 0ull;
  if (lane == nw - 1 && (n & 63)) w &= (1ull << (n & 63)) - 1ull;  // bits >= n are garbage
  __shared__ int lcnt[64];
  lcnt[lane] = __popcll(w);
  __syncthreads();
  int pre = 0;
  for (int t = 0; t < lane; t++) pre += lcnt[t];   // <=63 LDS adds, one wave — fine
  for (int b = 0; b < 64; b++) {
    int p = lane*64 + b;
    if (p < n) {
      pre += (int)((w >> b) & 1ull);
      pkc[pair*2048 + p] = pre;
    }
  }
}

// ---- K8: rank kept boxes via per-level prefix counts + 4 binary searches ----
__global__ void __launch_bounds__(256) k_out2(const unsigned long long* __restrict__ sel_key,
                      const float* __restrict__ sel_box,
                      const unsigned long long* __restrict__ keep,
                      const int* __restrict__ pkc,
                      float* __restrict__ out) {
  int img = blockIdx.y;
  int pos = blockIdx.x*256 + threadIdx.x;
  if (pos >= MTOT) return;
  int lvl = pos<2000?0 : pos<4000?1 : pos<6000?2 : pos<8000?3 : 4;
  int local = pos - SOFF[lvl];
  int pair = img*NLVL + lvl;
  unsigned long long kw = keep[(size_t)pair*MASK_W + (local >> 6)];
  if (!((kw >> (local & 63)) & 1ull)) return;
  unsigned long long mykey = sel_key[img*MTOT + pos];
  int rank = pkc[pair*2048 + local] - 1;    // kept before me within my level
  #pragma unroll
  for (int l2 = 0; l2 < NLVL; l2++) {
    if (l2 == lvl) continue;
    const unsigned long long* A = sel_key + img*MTOT + SOFF[l2];
    int lo = 0, hi = KSEL[l2];
    while (lo < hi) {
      int mid = (lo + hi) >> 1;
      if (A[mid] > mykey) lo = mid + 1; else hi = mid;
    }
    if (lo > 0) rank += pkc[(img*NLVL + l2)*2048 + lo - 1];
  }
  if (rank < OUTK) {
    ((float4*)out)[img*OUTK + rank] = ((const float4*)sel_box)[img*MTOT + pos];
    out[NIMG*OUTK*4 + img*OUTK + rank] = __uint_as_float((unsigned)(mykey >> 21));
  }
}

extern "C" void kernel_launch(void* const* d_in, const int* in_sizes, int n_in,
                              void* d_out, int out_size, void* d_ws, size_t ws_size,
                              hipStream_t stream) {
  Ins in;
  // setup_inputs dict order: cls_0, reg_0, cls_1, reg_1, ..., cls_4, reg_4, image_h, image_w
  for (int l = 0; l < 5; l++) {
    in.cls[l] = (const float*)d_in[2*l];
    in.reg[l] = (const float*)d_in[2*l + 1];
  }
  in.ih = (const int*)d_in[10];
  in.iw = (const int*)d_in[11];

  char* ws = (char*)d_ws;
  unsigned* hist              = (unsigned*)(ws + OFF_HIST);
  int* pkc                    = (int*)(ws + OFF_PKC);          // aliases hist (dead after k_scan)
  unsigned* cnt               = (unsigned*)(ws + OFF_CNT);
  unsigned* thr               = (unsigned*)(ws + OFF_THR);
  unsigned* cand              = (unsigned*)(ws + OFF_CAND);
  unsigned* sel_idx           = (unsigned*)(ws + OFF_SELIDX);
  unsigned long long* sel_key = (unsigned long long*)(ws + OFF_SELKEY);
  float* sel_sc               = (float*)(ws + OFF_SELSC);
  float* sel_box              = (float*)(ws + OFF_SELBOX);
  unsigned long long* maskbuf = (unsigned long long*)(ws + OFF_MASK);
  unsigned long long* ckey    = (unsigned long long*)(ws + OFF_CKEY);  // aliases maskbuf (dead before k_masks)
  unsigned long long* keep    = (unsigned long long*)(ws + OFF_KEEP);
  float* out                  = (float*)d_out;

  hipMemsetAsync(d_ws, 0, ZERO_BYTES, stream);                 // hist + counters + thr
  hipMemsetAsync(d_out, 0, (size_t)NIMG*OUTK*5*sizeof(float), stream); // zero-padded outputs

  k_hist   <<<NIMG*BLK_PER_IMG, 256, 0, stream>>>(in, hist);
  k_scan   <<<NPAIR, 256, 0, stream>>>(hist, thr);
  k_compact<<<NIMG*BLK_PER_IMG, 256, 0, stream>>>(in, thr, cnt, cand, ckey);
  k_rank   <<<dim3(CAP/256, NPAIR), 256, 0, stream>>>(cnt, cand, ckey, sel_idx, sel_key, sel_sc);
  k_decode <<<(NIMG*MTOT + 255)/256, 256, 0, stream>>>(in, sel_idx, sel_box);
  k_masks  <<<dim3(132, NPAIR), 256, 0, stream>>>(sel_box, maskbuf);
  k_nms    <<<NPAIR, 1024, 0, stream>>>(maskbuf, keep);
  k_pfx    <<<NPAIR, 64, 0, stream>>>(keep, pkc);
  k_out2   <<<dim3((MTOT + 255)/256, NIMG), 256, 0, stream>>>(sel_key, sel_box, keep, pkc, out);
}

// Round 19
// 277.529 us; speedup vs baseline: 1.6882x; 1.0215x over previous
//
#include <hip/hip_runtime.h>
#include <cmath>

// Match XLA/numpy non-fused mul+add rounding everywhere (IoU / decode bit-faithfulness).
#pragma clang fp contract(off)

namespace {
constexpr int NIMG = 8;
constexpr int NLVL = 5;
constexpr int LH[5]   = {208,104,52,26,13};
constexpr int LW[5]   = {336,168,84,42,21};
constexpr int LSTR[5] = {4,8,16,32,64};
constexpr int HWA[5]  = {209664,52416,13104,3276,819};
constexpr int KSEL[5] = {2000,2000,2000,2000,819};
constexpr int SOFF[5] = {0,2000,4000,6000,8000};
constexpr int MTOT    = 8819;
constexpr int CAP     = 6144;          // per-(img,lvl) candidate cap (expect <= ~2600)
constexpr int NPAIR   = NIMG*NLVL;     // 40
constexpr int CCUM[5] = {52,65,69,70,71};  // cumulative ceil(HWA/4096) per level
constexpr int BLK_PER_IMG = 71;
constexpr int MASK_W  = 32;            // u64 words per NMS mask row (covers 2048 cols)
constexpr int OUTK    = 1000;

// workspace byte offsets (all 16B-aligned where needed)
constexpr size_t OFF_HIST   = 0;              // 40*4096*4      = 655360
constexpr size_t OFF_PKC    = 0;              // 40*2048*4 = 327680, aliases hist (dead after k_scan)
constexpr size_t OFF_CNT    = 655360;         // 40*4           = 160
constexpr size_t OFF_THR    = 655520;         // 40*4           = 160
constexpr size_t ZERO_BYTES = 655680;         // memset range (hist+cnt+thr)
constexpr size_t OFF_CAND   = 655872;         // 40*6144*4      = 983040  -> 1638912
constexpr size_t OFF_SELIDX = 1638912;        // (unused now)
constexpr size_t OFF_SELKEY = 1921120;        // 8*8819*8       = 564416  -> 2485536
constexpr size_t OFF_SELSC  = 2485536;        // 8*8819*4       = 282208  -> 2767744
constexpr size_t OFF_SELBOX = 2767744;        // 8*8819*16      = 1128832 -> 3896576
constexpr size_t OFF_MASK   = 3896576;        // 40*2000*32*8   = 20480000-> 24376576
constexpr size_t OFF_CKEY   = OFF_MASK;       // 40*6144*8 = 1.97MB aliases maskbuf (dead by k_masks)
constexpr size_t OFF_KEEP   = 24376576;       // 40*32*8        = 10240   -> 24386816
}

struct Ins {
  const float* cls[5];
  const float* reg[5];
  const int* ih;
  const int* iw;
};

__device__ __forceinline__ void decode_block(int b, int& img, int& lvl, int& chunk) {
  img = b / BLK_PER_IMG;
  int rb = b - img*BLK_PER_IMG;
  if      (rb < CCUM[0]) { lvl=0; chunk=rb; }
  else if (rb < CCUM[1]) { lvl=1; chunk=rb-CCUM[0]; }
  else if (rb < CCUM[2]) { lvl=2; chunk=rb-CCUM[1]; }
  else if (rb < CCUM[3]) { lvl=3; chunk=rb-CCUM[2]; }
  else                   { lvl=4; chunk=0; }
}

// order-preserving float->u32 map (total order over floats)
__device__ __forceinline__ unsigned mapbits(float x) {
  unsigned u = __float_as_uint(x);
  return u ^ (unsigned)(((int)u >> 31) | (int)0x80000000);
}

// fp32 sigmoid with correctly-rounded exp step: matches 1/(1+exp_f32(-x)) pipeline
__device__ __forceinline__ float sigmoid_ref(float x) {
  float e = (float)exp(-(double)x);   // correctly-rounded f32 exp(-x)
  return 1.0f / (1.0f + e);           // exact-IEEE add + div
}

// ---- K1: per-(img,lvl) 12-bit histogram of mapped logit bits (float4 loads) ----
__global__ void k_hist(Ins in, unsigned* __restrict__ hist) {
  int img, lvl, chunk; decode_block(blockIdx.x, img, lvl, chunk);
  __shared__ unsigned lh[4096];
  for (int i = threadIdx.x; i < 4096; i += 256) lh[i] = 0;
  __syncthreads();
  const float* src = in.cls[lvl] + (size_t)img * HWA[lvl];
  if (lvl != 4) {                        // HWA divisible by 4, 16B-aligned per image
    const float4* src4 = (const float4*)src;
    int nf4 = HWA[lvl] >> 2;
    int base4 = chunk * 1024;
    #pragma unroll
    for (int j = 0; j < 4; j++) {
      int f = base4 + j*256 + threadIdx.x;
      if (f < nf4) {
        float4 v = src4[f];
        atomicAdd(&lh[mapbits(v.x) >> 20], 1u);
        atomicAdd(&lh[mapbits(v.y) >> 20], 1u);
        atomicAdd(&lh[mapbits(v.z) >> 20], 1u);
        atomicAdd(&lh[mapbits(v.w) >> 20], 1u);
      }
    }
  } else {                               // lvl 4: 819 elements, misaligned — scalar
    int base = chunk * 4096;
    #pragma unroll
    for (int j = 0; j < 16; j++) {
      int e = base + j*256 + threadIdx.x;
      if (e < HWA[4]) atomicAdd(&lh[mapbits(src[e]) >> 20], 1u);
    }
  }
  __syncthreads();
  unsigned* gh = hist + (img*NLVL + lvl) * 4096;
  for (int i = threadIdx.x; i < 4096; i += 256)
    if (lh[i]) atomicAdd(&gh[i], lh[i]);
}

// ---- K2: find highest bin-edge with suffix count >= k ----
__global__ void k_scan(const unsigned* __restrict__ hist, unsigned* __restrict__ thr) {
  int pair = blockIdx.x; int lvl = pair % NLVL;
  const unsigned* h = hist + (size_t)pair * 4096;
  __shared__ unsigned part[256];
  unsigned s = 0;
  #pragma unroll
  for (int i = 0; i < 16; i++) s += h[threadIdx.x*16 + i];
  part[threadIdx.x] = s;
  __syncthreads();
  if (threadIdx.x == 0) {
    unsigned k = (unsigned)KSEL[lvl];
    unsigned cum = 0;
    unsigned edge = 0;
    for (int t = 255; t >= 0; t--) {
      if (cum + part[t] >= k) {
        for (int b = t*16 + 15; b >= t*16; b--) {
          cum += h[b];
          if (cum >= k) { edge = (unsigned)b; break; }
        }
        thr[pair] = edge << 20;
        return;
      }
      cum += part[t];
    }
    thr[pair] = 0u;
  }
}

// ---- K3: compact candidates + compute sort keys in the same pass (float4 loads) ----
__global__ void __launch_bounds__(256) k_compact(Ins in, const unsigned* __restrict__ thr,
                          unsigned* __restrict__ cnt, unsigned* __restrict__ cand,
                          unsigned long long* __restrict__ ckey) {
  int img, lvl, chunk; decode_block(blockIdx.x, img, lvl, chunk);
  int pair = img*NLVL + lvl;
  unsigned T = thr[pair];
  const float* src = in.cls[lvl] + (size_t)img * HWA[lvl];
  int hw = LH[lvl] * LW[lvl];
  int lid = threadIdx.x & 63;
  __shared__ unsigned lbuf[4096];            // block covers <=4096 elements
  __shared__ unsigned long long lkey[4096];  // 32KB key staging
  __shared__ unsigned lc, gbase;
  if (threadIdx.x == 0) lc = 0;
  __syncthreads();

  auto emit = [&](int e, float v, bool sel) {
    unsigned long long mask = __ballot(sel);
    if (mask != 0ull) {
      int leader = __ffsll((long long)mask) - 1;
      unsigned wb = 0;
      if (lid == leader) wb = atomicAdd(&lc, (unsigned)__popcll(mask));  // LDS atomic
      wb = (unsigned)__shfl((int)wb, leader, 64);
      if (sel) {
        unsigned p = wb + (unsigned)__popcll(mask & ((1ull << lid) - 1ull));
        int a = e / hw;            // NCHW: e = a*hw + r
        int r = e - a*hw;
        unsigned idx = (unsigned)(r*3 + a);  // score-space idx
        lbuf[p] = idx;
        float s = sigmoid_ref(v);            // dp-exp on selected lanes only
        unsigned pack = ((unsigned)lvl << 18) | idx;   // < 2^21
        lkey[p] = ((unsigned long long)__float_as_uint(s) << 21)
                | (unsigned long long)(0x1FFFFFu - pack);  // desc score, asc (lvl,idx)
      }
    }
  };

  if (lvl != 4) {
    const float4* src4 = (const float4*)src;
    int nf4 = HWA[lvl] >> 2;
    int base4 = chunk * 1024;
    #pragma unroll
    for (int j = 0; j < 4; j++) {
      int f = base4 + j*256 + threadIdx.x;
      bool inb = f < nf4;
      float4 v4 = make_float4(0.f, 0.f, 0.f, 0.f);
      if (inb) v4 = src4[f];
      int e0 = f * 4;
      emit(e0+0, v4.x, inb && (mapbits(v4.x) >= T));
      emit(e0+1, v4.y, inb && (mapbits(v4.y) >= T));
      emit(e0+2, v4.z, inb && (mapbits(v4.z) >= T));
      emit(e0+3, v4.w, inb && (mapbits(v4.w) >= T));
    }
  } else {
    int base = chunk * 4096;
    #pragma unroll
    for (int j = 0; j < 16; j++) {
      int e = base + j*256 + threadIdx.x;
      float v = 0.0f;
      bool inb = (e < HWA[4]);
      if (inb) v = src[e];
      emit(e, v, inb && (mapbits(v) >= T));
    }
  }
  __syncthreads();
  if (threadIdx.x == 0) gbase = atomicAdd(&cnt[pair], lc);  // one global atomic/block
  __syncthreads();
  unsigned nsel = lc, gb = gbase;
  for (unsigned t = threadIdx.x; t < nsel; t += 256) {
    unsigned p = gb + t;
    if (p < CAP) {
      cand[(size_t)pair*CAP + p] = lbuf[t];                 // coalesced
      ckey[(size_t)pair*CAP + p] = lkey[t];
    }
  }
}

// ---- K4: per-level exact rank + FUSED box decode (mmdet DeltaXYWH, clipped) ----
__global__ void __launch_bounds__(256) k_rank(Ins in, const unsigned* __restrict__ cntA,
                       const unsigned* __restrict__ cand,
                       const unsigned long long* __restrict__ ckey,
                       unsigned long long* __restrict__ sel_key,
                       float* __restrict__ sel_sc,
                       float* __restrict__ sel_box) {
  int pair = blockIdx.y; int tile = blockIdx.x;
  int img = pair / NLVL, lvl = pair % NLVL;
  int c = min((int)cntA[pair], CAP);
  if (tile*256 >= c) return;
  __shared__ unsigned long long keys[CAP];
  const unsigned long long* kp = ckey + (size_t)pair*CAP;
  for (int j = threadIdx.x; j < c; j += 256) keys[j] = kp[j];
  __syncthreads();
  int jj = tile*256 + threadIdx.x;
  if (jj >= c) return;
  unsigned long long mykey = keys[jj];
  int rk = 0;
  for (int j = 0; j < c; j++) rk += (keys[j] > mykey) ? 1 : 0;  // LDS broadcast
  if (rk < KSEL[lvl]) {
    int slot = img*MTOT + SOFF[lvl] + rk;
    sel_key[slot] = mykey;
    sel_sc[slot]  = __uint_as_float((unsigned)(mykey >> 21));
    // fused decode (was k_decode): idx in hand
    unsigned idx = cand[(size_t)pair*CAP + jj];
    int a = (int)(idx % 3u);
    int r = (int)(idx / 3u);
    int Wl = LW[lvl]; int hw = LH[lvl]*Wl;
    int x = r % Wl, y = r / Wl;
    const float* rg = in.reg[lvl] + (size_t)img * 4 * HWA[lvl];  // 12*H*W
    float dx = rg[(a*4+0)*hw + r];
    float dy = rg[(a*4+1)*hw + r];
    float dw = rg[(a*4+2)*hw + r];
    float dh = rg[(a*4+3)*hw + r];
    float ratio = (a==0) ? 0.5f : (a==1) ? 1.0f : 2.0f;
    float hr = sqrtf(ratio);
    float wr = 1.0f / hr;
    float st = (float)LSTR[lvl];
    float wsz = st * wr * 8.0f;
    float hsz = st * hr * 8.0f;
    float xs = (float)x * st, ys = (float)y * st;
    float x1 = xs - wsz*0.5f, x2 = xs + wsz*0.5f;
    float y1 = ys - hsz*0.5f, y2 = ys + hsz*0.5f;
    float px = (x1 + x2) * 0.5f, py = (y1 + y2) * 0.5f;
    float pw = x2 - x1,          ph = y2 - y1;
    const float MR = 4.135166556742356f;
    dw = fminf(fmaxf(dw, -MR), MR);
    dh = fminf(fmaxf(dh, -MR), MR);
    float gx = px + pw*dx, gy = py + ph*dy;
    float gw = pw * (float)exp((double)dw);   // correctly-rounded f32 exp
    float gh = ph * (float)exp((double)dh);
    float Wi = (float)(*in.iw), Hi = (float)(*in.ih);
    float4 bb;
    bb.x = fminf(fmaxf(gx - gw*0.5f, 0.0f), Wi);
    bb.y = fminf(fmaxf(gy - gh*0.5f, 0.0f), Hi);
    bb.z = fminf(fmaxf(gx + gw*0.5f, 0.0f), Wi);
    bb.w = fminf(fmaxf(gy + gh*0.5f, 0.0f), Hi);
    ((float4*)sel_box)[slot] = bb;
  }
}

// ---- K6: NMS suppression-mask build — ballot tiles, 64 cols x 64 rows/wave ----
// EXACT branch-free IoU>0.7 via f64 (Md = midpoint(0.7f, succ(0.7f))); OOB
// columns degenerate; diagonal tiles take a separate masked loop.
__global__ void __launch_bounds__(256) k_masks(const float* __restrict__ sel_box,
                        unsigned long long* __restrict__ maskbuf) {
  int pair = blockIdx.y; int lvl = pair % NLVL; int img = pair / NLVL;
  int n = KSEL[lvl];
  int nw = (n + 63) >> 6;
  int wv = threadIdx.x >> 6;
  int lane = threadIdx.x & 63;
  int t = blockIdx.x * 4 + wv;           // flat triangular tile id
  int ntile = nw * (nw + 1) / 2;
  if (t >= ntile) return;                // wave-level exit (no barriers used)
  int rb = 0, cum = 0;
  while (cum + (nw - rb) <= t) { cum += nw - rb; rb++; }
  int jw = rb + (t - cum);               // word strip; jw >= rb (upper-tri)
  const float4* boxes = ((const float4*)sel_box) + img*MTOT + SOFF[lvl];
  float off = (float)lvl * 4096.0f;
  int col = jw*64 + lane;
  float bjx, bjy, bjz, bjw2, aj;
  if (col < n) {
    float4 bj = boxes[col];
    bjx = bj.x + off; bjy = bj.y + off; bjz = bj.z + off; bjw2 = bj.w + off;
    aj = (bjz - bjx) * (bjw2 - bjy);
  } else {
    bjx = 3.0e8f; bjy = 3.0e8f; bjz = 3.0e8f; bjw2 = 3.0e8f;   // inter=0, aj=0
    aj = 0.0f;
  }
  __shared__ float4 srow[4][64];
  int row0 = rb*64;
  {
    float4 bi0 = boxes[min(row0 + lane, n-1)];
    bi0.x += off; bi0.y += off; bi0.z += off; bi0.w += off;
    srow[wv][lane] = bi0;
  }
  const double Md = 0.70000001788139343261718750;  // (0.7f + succ(0.7f))/2 exact
  unsigned long long acc = 0ull;
  if (jw > rb) {
    #pragma unroll 16
    for (int r = 0; r < 64; r++) {
      float4 bi = srow[wv][r];           // LDS broadcast (uniform address)
      float ai = (bi.z - bi.x) * (bi.w - bi.y);
      float xx1 = fmaxf(bi.x, bjx), yy1 = fmaxf(bi.y, bjy);
      float xx2 = fminf(bi.z, bjz), yy2 = fminf(bi.w, bjw2);
      float iw_ = fmaxf(xx2 - xx1, 0.0f), ih_ = fmaxf(yy2 - yy1, 0.0f);
      float inter = iw_ * ih_;
      float u = fmaxf((ai + aj) - inter, 1e-6f);
      bool sup = (double)inter >= Md * (double)u;  // exact rn(inter/u) > 0.7f
      unsigned long long word = __ballot(sup);
      if (lane == r) acc = word;
    }
  } else {
    #pragma unroll 16
    for (int r = 0; r < 64; r++) {
      float4 bi = srow[wv][r];
      float ai = (bi.z - bi.x) * (bi.w - bi.y);
      float xx1 = fmaxf(bi.x, bjx), yy1 = fmaxf(bi.y, bjy);
      float xx2 = fminf(bi.z, bjz), yy2 = fminf(bi.w, bjw2);
      float iw_ = fmaxf(xx2 - xx1, 0.0f), ih_ = fmaxf(yy2 - yy1, 0.0f);
      float inter = iw_ * ih_;
      float u = fmaxf((ai + aj) - inter, 1e-6f);
      bool sup = (double)inter >= Md * (double)u;
      unsigned long long word = __ballot(sup) & ~((2ull << r) - 1ull);  // j > i (SALU)
      if (lane == r) acc = word;
    }
  }
  if (row0 + lane < n)
    maskbuf[(size_t)pair*2000*MASK_W + (size_t)(row0 + lane)*MASK_W + jw] = acc;
}

// ---- K7: EXACT one-pass block-sequential greedy NMS + FUSED prefix counts ----
// Register double-buffered loads, wave-0 in-block register Jacobi, LDS rem
// accumulate. Tail: wave 0 computes the per-level inclusive kept-prefix (was
// k_pfx) from LDS-resident keep words — one fewer launch + no keep re-read.
__global__ void __launch_bounds__(1024) k_nms(const unsigned long long* __restrict__ maskbuf,
                      unsigned long long* __restrict__ keep, int* __restrict__ pkc) {
  int pair = blockIdx.x; int lvl = pair % NLVL;
  int n = KSEL[lvl];
  int nw = (n + 63) >> 6;
  const unsigned long long* mrow = maskbuf + (size_t)pair*2000*MASK_W;
  int tid = threadIdx.x;
  int w  = tid & 31;                 // word owned (0..31)
  int rg = tid >> 5;                 // row group (0..31): rows rg*2, rg*2+1
  __shared__ unsigned long long rem[32];   // suppression from finalized kept boxes
  __shared__ unsigned long long diag[64];  // word k of current block's rows
  __shared__ unsigned long long skw[32];   // kept words (for fused pfx)
  __shared__ unsigned long long sSk;       // final suppressed mask of block k
  __shared__ int lcnt[64];
  if (tid < 32) { rem[tid] = 0ull; skw[tid] = 0ull; }
  __syncthreads();

  unsigned long long A0, A1, B0, B1;
  {
    int r0 = min(rg*2, n-1), r1 = min(rg*2+1, n-1);
    A0 = mrow[(size_t)r0*MASK_W + w];
    A1 = mrow[(size_t)r1*MASK_W + w];
  }
  for (int k = 0; k < nw; k++) {
    if (k + 1 < nw) {                // prefetch block k+1 (consumed next iter)
      int r0 = min(64*(k+1) + rg*2, n-1), r1 = min(64*(k+1) + rg*2 + 1, n-1);
      B0 = mrow[(size_t)r0*MASK_W + w];
      B1 = mrow[(size_t)r1*MASK_W + w];
    }
    if (w == k) { diag[rg*2] = A0; diag[rg*2+1] = A1; }
    __syncthreads();
    if (tid < 64) {                  // wave 0: in-block register Jacobi
      int row = 64*k + tid;
      bool valid = row < n;
      unsigned long long D = valid ? diag[tid] : 0ull;   // already strictly upper
      unsigned long long rk = rem[k];
      unsigned long long S = rk;
      for (int it = 0; it < 64; it++) {
        bool kept = valid && !((S >> tid) & 1ull);
        unsigned long long c = kept ? D : 0ull;
        #pragma unroll
        for (int m = 1; m < 64; m <<= 1) {               // wave-wide OR
          unsigned lo = (unsigned)__shfl_xor((int)(unsigned)(c & 0xffffffffull), m, 64);
          unsigned hi = (unsigned)__shfl_xor((int)(unsigned)(c >> 32), m, 64);
          c |= ((unsigned long long)hi << 32) | (unsigned long long)lo;
        }
        unsigned long long Snew = rk | c;                // uniform across wave
        if (Snew == S) break;                            // fixpoint (<= depth iters)
        S = Snew;
      }
      if (tid == 0) {
        sSk = S;
        int nb = n - 64*k;
        unsigned long long vm = (nb >= 64) ? ~0ull : ((1ull << nb) - 1ull);
        unsigned long long kw = (~S) & vm;
        skw[k] = kw;
        keep[(size_t)pair*MASK_W + k] = kw;
      }
    }
    __syncthreads();
    if (w > k) {                     // accumulate alive rows into later words
      unsigned long long Sk = sSk;
      int r0 = 64*k + rg*2, r1 = r0 + 1;
      unsigned long long m = 0ull;
      if (r0 < n && !((Sk >> (rg*2)) & 1ull))     m |= A0;
      if (r1 < n && !((Sk >> (rg*2+1)) & 1ull))   m |= A1;
      if (m) atomicOr(&rem[w], m);
    }
    __syncthreads();
    A0 = B0; A1 = B1;
  }
  // ---- fused prefix counts (was k_pfx); wave 0, skw already masked ----
  if (tid < 64) {
    int lane = tid;
    unsigned long long kw = (lane < nw) ? skw[lane] : 0ull;
    lcnt[lane] = __popcll(kw);       // wave-synchronous LDS (no barrier needed)
    int pre = 0;
    for (int t2 = 0; t2 < lane; t2++) pre += lcnt[t2];
    for (int b = 0; b < 64; b++) {
      int p = lane*64 + b;
      if (p < n) {
        pre += (int)((kw >> b) & 1ull);
        pkc[pair*2048 + p] = pre;
      }
    }
  }
}

// ---- K8: rank kept boxes via per-level prefix counts + 4 binary searches ----
__global__ void __launch_bounds__(256) k_out2(const unsigned long long* __restrict__ sel_key,
                      const float* __restrict__ sel_box,
                      const unsigned long long* __restrict__ keep,
                      const int* __restrict__ pkc,
                      float* __restrict__ out) {
  int img = blockIdx.y;
  int pos = blockIdx.x*256 + threadIdx.x;
  if (pos >= MTOT) return;
  int lvl = pos<2000?0 : pos<4000?1 : pos<6000?2 : pos<8000?3 : 4;
  int local = pos - SOFF[lvl];
  int pair = img*NLVL + lvl;
  unsigned long long kw = keep[(size_t)pair*MASK_W + (local >> 6)];
  if (!((kw >> (local & 63)) & 1ull)) return;
  unsigned long long mykey = sel_key[img*MTOT + pos];
  int rank = pkc[pair*2048 + local] - 1;    // kept before me within my level
  #pragma unroll
  for (int l2 = 0; l2 < NLVL; l2++) {
    if (l2 == lvl) continue;
    const unsigned long long* A = sel_key + img*MTOT + SOFF[l2];
    int lo = 0, hi = KSEL[l2];
    while (lo < hi) {
      int mid = (lo + hi) >> 1;
      if (A[mid] > mykey) lo = mid + 1; else hi = mid;
    }
    if (lo > 0) rank += pkc[(img*NLVL + l2)*2048 + lo - 1];
  }
  if (rank < OUTK) {
    ((float4*)out)[img*OUTK + rank] = ((const float4*)sel_box)[img*MTOT + pos];
    out[NIMG*OUTK*4 + img*OUTK + rank] = __uint_as_float((unsigned)(mykey >> 21));
  }
}

extern "C" void kernel_launch(void* const* d_in, const int* in_sizes, int n_in,
                              void* d_out, int out_size, void* d_ws, size_t ws_size,
                              hipStream_t stream) {
  Ins in;
  // setup_inputs dict order: cls_0, reg_0, cls_1, reg_1, ..., cls_4, reg_4, image_h, image_w
  for (int l = 0; l < 5; l++) {
    in.cls[l] = (const float*)d_in[2*l];
    in.reg[l] = (const float*)d_in[2*l + 1];
  }
  in.ih = (const int*)d_in[10];
  in.iw = (const int*)d_in[11];

  char* ws = (char*)d_ws;
  unsigned* hist              = (unsigned*)(ws + OFF_HIST);
  int* pkc                    = (int*)(ws + OFF_PKC);          // aliases hist (dead after k_scan)
  unsigned* cnt               = (unsigned*)(ws + OFF_CNT);
  unsigned* thr               = (unsigned*)(ws + OFF_THR);
  unsigned* cand              = (unsigned*)(ws + OFF_CAND);
  unsigned long long* sel_key = (unsigned long long*)(ws + OFF_SELKEY);
  float* sel_sc               = (float*)(ws + OFF_SELSC);
  float* sel_box              = (float*)(ws + OFF_SELBOX);
  unsigned long long* maskbuf = (unsigned long long*)(ws + OFF_MASK);
  unsigned long long* ckey    = (unsigned long long*)(ws + OFF_CKEY);  // aliases maskbuf (dead before k_masks)
  unsigned long long* keep    = (unsigned long long*)(ws + OFF_KEEP);
  float* out                  = (float*)d_out;

  hipMemsetAsync(d_ws, 0, ZERO_BYTES, stream);                 // hist + counters + thr
  hipMemsetAsync(d_out, 0, (size_t)NIMG*OUTK*5*sizeof(float), stream); // zero-padded outputs

  k_hist   <<<NIMG*BLK_PER_IMG, 256, 0, stream>>>(in, hist);
  k_scan   <<<NPAIR, 256, 0, stream>>>(hist, thr);
  k_compact<<<NIMG*BLK_PER_IMG, 256, 0, stream>>>(in, thr, cnt, cand, ckey);
  k_rank   <<<dim3(CAP/256, NPAIR), 256, 0, stream>>>(in, cnt, cand, ckey, sel_key, sel_sc, sel_box);
  k_masks  <<<dim3(132, NPAIR), 256, 0, stream>>>(sel_box, maskbuf);
  k_nms    <<<NPAIR, 1024, 0, stream>>>(maskbuf, keep, pkc);
  k_out2   <<<dim3((MTOT + 255)/256, NIMG), 256, 0, stream>>>(sel_key, sel_box, keep, pkc, out);
}